// Round 13
// baseline (92.965 us; speedup 1.0000x reference)
//
#include <hip/hip_runtime.h>
#include <math.h>

#define TK 30
#define TH 128
#define TNIN 256
#define TDFF 512
#define NTOK 8000
#define ROWP 264   // KVs row stride in u16

typedef __attribute__((ext_vector_type(8))) short short8v;
typedef __attribute__((ext_vector_type(4))) short short4v;
typedef __attribute__((ext_vector_type(4))) float f32x4;

constexpr float LN_EPS = 1e-6f;
constexpr float NEG_INF = -3.402823466e38f;
constexpr float INV_SQRT_D = 0.17677669529663687f;  // 1/sqrt(32)

static __device__ __forceinline__ unsigned short f2bf(float f) {
  unsigned u = __float_as_uint(f);
  u = u + 0x7fffu + ((u >> 16) & 1u);
  return (unsigned short)(u >> 16);
}
static __device__ __forceinline__ float bf2f(unsigned short s) {
  return __uint_as_float(((unsigned)s) << 16);
}
static __device__ __forceinline__ void gload16(const void* gsrc, void* ldst) {
  __builtin_amdgcn_global_load_lds(
      (const __attribute__((address_space(1))) unsigned int*)gsrc,
      (__attribute__((address_space(3))) unsigned int*)ldst, 16, 0, 0);
}

// ---------------------------------------------------------------------------
// K0: weight prep (verbatim R12, verified). Frag-linear bf16:
//   elem ((ks*NF + n)*64 + lane)*8 + j = W[n*16+(lane&15)][ks*32+(lane>>4)*8+j]
// ---------------------------------------------------------------------------
__global__ void conv_weights_kernel(const float* __restrict__ W_K,
                                    const float* __restrict__ W_V,
                                    const float* __restrict__ W_Q,
                                    const float* __restrict__ W_O,
                                    const float* __restrict__ W_in,
                                    const float* __restrict__ W_out,
                                    unsigned short* __restrict__ Wc2,
                                    unsigned short* __restrict__ Wq2,
                                    unsigned short* __restrict__ Wp2,
                                    unsigned short* __restrict__ Wi2,
                                    unsigned short* __restrict__ Wo2)
{
  int idx = blockIdx.x * 256 + threadIdx.x;   // 0..229375
  if (idx < 65536) {
    int e = idx >> 3, j = idx & 7;
    int kk = e >> 10, n = (e >> 6) & 15, lane = e & 63;
    int r = n*16 + (lane & 15);
    int c = kk*32 + (lane >> 4)*8 + j;
    float v = (r < TH) ? W_K[(size_t)r*TNIN + c] : W_V[(size_t)(r-TH)*TNIN + c];
    Wc2[idx] = f2bf(v);
  } else if (idx < 81920) {
    int i2 = idx - 65536;
    int e = i2 >> 3, j = i2 & 7;
    int kk = e >> 9, n = (e >> 6) & 7, lane = e & 63;
    int r = n*16 + (lane & 15);
    int c = kk*32 + (lane >> 4)*8 + j;
    Wq2[i2] = f2bf(W_Q[(size_t)r*TH + c]);
  } else if (idx < 98304) {
    int ip = idx - 81920;
    int e = ip >> 3, j = ip & 7;
    int kk = e >> 9, n = (e >> 6) & 7, lane = e & 63;
    int r = n*16 + (lane & 15);
    int c = kk*32 + (lane >> 4)*8 + j;
    Wp2[ip] = f2bf(W_O[(size_t)r*TH + c]);
  } else if (idx < 163840) {
    int i3 = idx - 98304;
    int e = i3 >> 3, j = i3 & 7;
    int ks = e >> 11, n = (e >> 6) & 31, lane = e & 63;
    int r = n*16 + (lane & 15);
    int c = ks*32 + (lane >> 4)*8 + j;
    Wi2[i3] = f2bf(W_in[(size_t)r*TH + c]);
  } else {
    int i4 = idx - 163840;
    int e = i4 >> 3, j = i4 & 7;
    int ks = e >> 9, n = (e >> 6) & 7, lane = e & 63;
    int r = n*16 + (lane & 15);
    int c = ks*32 + (lane >> 4)*8 + j;
    Wo2[i4] = f2bf(W_out[(size_t)r*TDFF + c]);
  }
}

// ---------------------------------------------------------------------------
// K1: fused Q-proj + KV-GEMM + attention core — R13 FAT-WAVE remap.
// 256 threads (4 waves); wave nq owns M128 x N64 (acc 8x4 frags = 128 VGPR).
// Every B byte read ONCE (was 2x); MFMA:LDS-read 32:12 (was 16:8).
// LDS layout byte-identical to R12. vmcnt schedule {8,12,...,12,8,0} audited
// for the 4-loads-per-issue granularity.
// ---------------------------------------------------------------------------
__global__ __launch_bounds__(256, 2) void kvattn_kernel(
    const float* __restrict__ A, const unsigned short* __restrict__ Wc2,
    const unsigned short* __restrict__ Wq2, const float* __restrict__ h_v,
    const float* __restrict__ mask_attend, float* __restrict__ ul)
{
  const int tid  = threadIdx.x;
  const int nq   = tid >> 6;    // wave 0..3 = N-quarter
  const int lane = tid & 63;
  const int lm   = lane & 15;
  const int lgp  = lane >> 4;
  const int bn0  = blockIdx.x * 4;

  __shared__ __align__(16) char smem[73728];
  unsigned short* Bl  = (unsigned short*)smem;          // [3][8192]   0..49152
  unsigned short* Al  = (unsigned short*)(smem + 49152);// [2][128][40] ..69632
  unsigned short* KVs = (unsigned short*)smem;          // [128][264] overlay 0..67584
  float* att = (float*)(smem + 67584);                  // [4][4][32] (Al tail, dead)
  float* hvp = (float*)(smem + 69632);                  // [4][128] f32
  float* qvp = (float*)(smem + 71680);                  // [4][128] f32

  // ---- prologue extras: h_v to LDS ----
  if (tid < 128) {
    int tok = tid >> 5, q = tid & 31;
    *(float4*)&hvp[tok*128 + q*4] = *(const float4*)&h_v[(size_t)(bn0 + tok)*TH + q*4];
  }

  // A staging: thread stages 16 f32 = row (tid>>1), col half (tid&1)*16
  const int rowa = tid >> 1, ha = tid & 1;
  const int rowc = (rowa > 119) ? 119 : rowa;
  const float* aptr = A + ((size_t)blockIdx.x*120 + rowc)*TNIN + ha*16;

  #define ISSUE_B(K)                                                               \
    { gload16(Wc2 + (size_t)(K)*8192 + (tid      )*8, &Bl[((K)%3)*8192 + (tid      )*8]); \
      gload16(Wc2 + (size_t)(K)*8192 + (tid+ 256 )*8, &Bl[((K)%3)*8192 + (tid+ 256 )*8]); \
      gload16(Wc2 + (size_t)(K)*8192 + (tid+ 512 )*8, &Bl[((K)%3)*8192 + (tid+ 512 )*8]); \
      gload16(Wc2 + (size_t)(K)*8192 + (tid+ 768 )*8, &Bl[((K)%3)*8192 + (tid+ 768 )*8]); }

  #define LOAD_RA(S, K)                                                     \
    { ra[S][0] = *(const float4*)(aptr + (K)*32);                           \
      ra[S][1] = *(const float4*)(aptr + (K)*32 + 4);                       \
      ra[S][2] = *(const float4*)(aptr + (K)*32 + 8);                       \
      ra[S][3] = *(const float4*)(aptr + (K)*32 + 12); }

  #define WRITE_A(K, S)                                                     \
    { short8v w0, w1;                                                       \
      w0[0]=(short)f2bf(ra[S][0].x); w0[1]=(short)f2bf(ra[S][0].y);         \
      w0[2]=(short)f2bf(ra[S][0].z); w0[3]=(short)f2bf(ra[S][0].w);         \
      w0[4]=(short)f2bf(ra[S][1].x); w0[5]=(short)f2bf(ra[S][1].y);         \
      w0[6]=(short)f2bf(ra[S][1].z); w0[7]=(short)f2bf(ra[S][1].w);         \
      w1[0]=(short)f2bf(ra[S][2].x); w1[1]=(short)f2bf(ra[S][2].y);         \
      w1[2]=(short)f2bf(ra[S][2].z); w1[3]=(short)f2bf(ra[S][2].w);         \
      w1[4]=(short)f2bf(ra[S][3].x); w1[5]=(short)f2bf(ra[S][3].y);         \
      w1[6]=(short)f2bf(ra[S][3].z); w1[7]=(short)f2bf(ra[S][3].w);         \
      *(short8v*)&Al[(((K)&1)*128 + rowa)*40 + ha*16    ] = w0;             \
      *(short8v*)&Al[(((K)&1)*128 + rowa)*40 + ha*16 + 8] = w1; }

  float4 ra[3][4];
  f32x4 acc[8][4] = {};

  // prologue: rA(0); B(0); B(1); rA(1); rA(2); write A(0)
  LOAD_RA(0, 0);
  ISSUE_B(0);
  ISSUE_B(1);
  LOAD_RA(1, 1);
  LOAD_RA(2, 2);
  WRITE_A(0, 0);

  #pragma unroll
  for (int k = 0; k < 8; ++k) {
    // audit (4-item granularity): steady = rA + B + rA younger = 12
    if      (k == 0) asm volatile("s_waitcnt vmcnt(8)"  ::: "memory");
    else if (k <= 5) asm volatile("s_waitcnt vmcnt(12)" ::: "memory");
    else if (k == 6) asm volatile("s_waitcnt vmcnt(8)"  ::: "memory");
    else             asm volatile("s_waitcnt vmcnt(0)"  ::: "memory");
    __builtin_amdgcn_s_barrier();

    if (k < 6) ISSUE_B(k+2);
    if (k < 5) LOAD_RA(k%3, k+3);

    short8v af[8];
    #pragma unroll
    for (int m = 0; m < 8; ++m)
      af[m] = *(const short8v*)&Al[((k&1)*128 + m*16 + lm)*40 + lgp*8];

    __builtin_amdgcn_s_setprio(1);
    #pragma unroll
    for (int n = 0; n < 4; ++n) {
      short8v b = *(const short8v*)&Bl[(k%3)*8192 + ((nq*4 + n)*64 + lane)*8];
      #pragma unroll
      for (int m = 0; m < 8; ++m)
        acc[m][n] = __builtin_amdgcn_mfma_f32_16x16x32_bf16(b, af[m], acc[m][n], 0, 0, 0);
    }
    __builtin_amdgcn_s_setprio(0);

    if (k < 7) WRITE_A(k+1, (k+1)%3);
  }
  #undef ISSUE_B
  #undef LOAD_RA
  #undef WRITE_A

  __syncthreads();   // all Bl/Al reads done before KVs overlay

  // ---- C writeout (verified swapped-operand mapping) ----
  #pragma unroll
  for (int m = 0; m < 8; ++m) {
    int row = m*16 + lm;
    #pragma unroll
    for (int n = 0; n < 4; ++n) {
      int col = (nq*4 + n)*16 + lgp*4;
      short4v p;
      p[0]=(short)f2bf(acc[m][n][0]); p[1]=(short)f2bf(acc[m][n][1]);
      p[2]=(short)f2bf(acc[m][n][2]); p[3]=(short)f2bf(acc[m][n][3]);
      *(short4v*)&KVs[row*ROWP + col] = p;
    }
  }

  // ---- Q = h_v @ W_Q^T (acc dead; wave covers 2 col-frags: 4x2x16=128) ----
  {
    const int tokc = (lm < 4) ? lm : 3;
    #pragma unroll
    for (int nf = 0; nf < 2; ++nf) {
      f32x4 qacc = {};
      #pragma unroll
      for (int ks = 0; ks < 4; ++ks) {
        short8v wq = *(const short8v*)(Wq2 + ((size_t)(ks*8 + nq*2 + nf)*64 + lane)*8);
        const float* hp = hvp + tokc*128 + ks*32 + lgp*8;
        float4 lo = *(const float4*)hp;
        float4 hi = *(const float4*)(hp + 4);
        short8v ha_;
        ha_[0]=(short)f2bf(lo.x); ha_[1]=(short)f2bf(lo.y);
        ha_[2]=(short)f2bf(lo.z); ha_[3]=(short)f2bf(lo.w);
        ha_[4]=(short)f2bf(hi.x); ha_[5]=(short)f2bf(hi.y);
        ha_[6]=(short)f2bf(hi.z); ha_[7]=(short)f2bf(hi.w);
        qacc = __builtin_amdgcn_mfma_f32_16x16x32_bf16(wq, ha_, qacc, 0, 0, 0);
      }
      if (lm < 4) *(f32x4*)&qvp[lm*128 + (nq*2 + nf)*16 + lgp*4] = qacc;
    }
  }
  __syncthreads();   // KVs + qvp visible

  // ---- logits + masked softmax (2 passes: 256 threads cover 4 tokens) ----
  #pragma unroll
  for (int pass = 0; pass < 2; ++pass) {
    int tok = (tid >> 7) + 2*pass, h = (tid >> 5) & 3, k = tid & 31;
    int gtok = bn0 + tok;
    float s = 0.f;
    float ma = 0.f;
    if (k < TK) {
      const float* qp = &qvp[tok*128 + h*32];
      const unsigned short* kp = &KVs[(tok*TK + k)*ROWP + h*32];
      #pragma unroll
      for (int j = 0; j < 4; ++j) {
        short8v kf = *(const short8v*)(kp + j*8);
        float4 qa = *(const float4*)(qp + j*8);
        float4 qb = *(const float4*)(qp + j*8 + 4);
        s += qa.x*bf2f((unsigned short)kf[0]) + qa.y*bf2f((unsigned short)kf[1])
           + qa.z*bf2f((unsigned short)kf[2]) + qa.w*bf2f((unsigned short)kf[3])
           + qb.x*bf2f((unsigned short)kf[4]) + qb.y*bf2f((unsigned short)kf[5])
           + qb.z*bf2f((unsigned short)kf[6]) + qb.w*bf2f((unsigned short)kf[7]);
      }
      ma = mask_attend[(size_t)gtok*TK + k];
    }
    bool ok = (k < TK) && (ma > 0.f);
    float val = ok ? s * INV_SQRT_D : NEG_INF;
    float mm = val;
    #pragma unroll
    for (int d = 16; d >= 1; d >>= 1) mm = fmaxf(mm, __shfl_xor(mm, d, 32));
    float e = ok ? expf(val - mm) : 0.f;
    float ss = e;
    #pragma unroll
    for (int d = 16; d >= 1; d >>= 1) ss += __shfl_xor(ss, d, 32);
    att[(tok*4 + h)*32 + k] = e / ss;
  }
  __syncthreads();

  // ---- PV (2 passes) ----
  #pragma unroll
  for (int pass = 0; pass < 2; ++pass) {
    int tok = (tid >> 7) + 2*pass, c = tid & 127;
    int gtok = bn0 + tok;
    const float* ar = &att[(tok*4 + (c >> 5))*32];
    const unsigned short* vb = &KVs[tok*TK*ROWP + TH + c];
    float u = 0.f;
    #pragma unroll
    for (int k = 0; k < TK; ++k)
      u += ar[k] * bf2f(vb[k*ROWP]);
    ul[(size_t)gtok*TH + c] = u;
  }
}

// ---------------------------------------------------------------------------
// K2: ffn_all (verbatim R11/R12, verified).
// ---------------------------------------------------------------------------
__global__ __launch_bounds__(256) void ffn_all_kernel(
    const float* __restrict__ ul, const unsigned short* __restrict__ Wp2,
    const float* __restrict__ h_v,
    const float* __restrict__ gain0, const float* __restrict__ bias0,
    const unsigned short* __restrict__ Wi2, const unsigned short* __restrict__ Wo2,
    const float* __restrict__ b_in, const float* __restrict__ b_out,
    const float* __restrict__ gain1, const float* __restrict__ bias1,
    const float* __restrict__ mask_v, float* __restrict__ out)
{
  const int tid  = threadIdx.x;
  const int tok0 = blockIdx.x * 32;
  const int wave = tid >> 6;
  const int lane = tid & 63;
  const int lm   = lane & 15;
  const int lgp  = lane >> 4;

  __shared__ __align__(16) char smem[143616];
  unsigned short* Wp  = (unsigned short*)smem;            // 32 KB
  unsigned short* Wst = (unsigned short*)(smem + 32768);  // 64 KB dbuf
  unsigned short* At  = (unsigned short*)(smem + 98304);  // [32][136]
  unsigned short* Zs  = (unsigned short*)(smem + 107008); // [32][520]
  float* bin  = (float*)(smem + 140288);
  float* part = (float*)(smem + 142336);
  float* red  = (float*)(smem + 143360);

  for (int t = tid; t < 1024; t += 256) {
    int row = t >> 5, q = t & 31;
    float4 v = *(const float4*)&ul[(size_t)(tok0+row)*TH + q*4];
    short4v w;
    w[0]=(short)f2bf(v.x); w[1]=(short)f2bf(v.y);
    w[2]=(short)f2bf(v.z); w[3]=(short)f2bf(v.w);
    *(short4v*)&At[row*136 + q*4] = w;
  }
  if (tid < 128) *(float4*)&bin[tid*4] = *(const float4*)&b_in[tid*4];
  #pragma unroll
  for (int p = 0; p < 8; ++p)
    gload16(Wp2 + (size_t)(tid + p*256)*8, &Wp[(tid + p*256)*8]);
  #pragma unroll
  for (int p = 0; p < 8; ++p)
    gload16(Wi2 + (size_t)(tid + p*256)*8, &Wst[(tid + p*256)*8]);

  asm volatile("s_waitcnt vmcnt(8)" ::: "memory");
  __syncthreads();

  f32x4 acco[2][2] = {};
  #pragma unroll
  for (int ks = 0; ks < 4; ++ks) {
    short8v a0 = *(const short8v*)&At[lm*136      + ks*32 + lgp*8];
    short8v a1 = *(const short8v*)&At[(16+lm)*136 + ks*32 + lgp*8];
    #pragma unroll
    for (int n = 0; n < 2; ++n) {
      short8v b = *(const short8v*)&Wp[((size_t)(ks*8 + wave*2 + n)*64 + lane)*8];
      acco[0][n] = __builtin_amdgcn_mfma_f32_16x16x32_bf16(b, a0, acco[0][n], 0, 0, 0);
      acco[1][n] = __builtin_amdgcn_mfma_f32_16x16x32_bf16(b, a1, acco[1][n], 0, 0, 0);
    }
  }

  f32x4 hn[2][2];
  {
    f32x4 x[2][2];
    float s1r[2] = {0.f, 0.f}, s2r[2] = {0.f, 0.f};
    #pragma unroll
    for (int m = 0; m < 2; ++m) {
      int row = m*16 + lm;
      #pragma unroll
      for (int n = 0; n < 2; ++n) {
        int col = (wave*2 + n)*16 + lgp*4;
        float4 hv = *(const float4*)&h_v[(size_t)(tok0+row)*TH + col];
        x[m][n][0] = acco[m][n][0] + hv.x;
        x[m][n][1] = acco[m][n][1] + hv.y;
        x[m][n][2] = acco[m][n][2] + hv.z;
        x[m][n][3] = acco[m][n][3] + hv.w;
        #pragma unroll
        for (int r = 0; r < 4; ++r) {
          s1r[m] += x[m][n][r];
          s2r[m] += x[m][n][r]*x[m][n][r];
        }
      }
    }
    #pragma unroll
    for (int m = 0; m < 2; ++m) {
      s1r[m] += __shfl_xor(s1r[m], 16); s2r[m] += __shfl_xor(s2r[m], 16);
      s1r[m] += __shfl_xor(s1r[m], 32); s2r[m] += __shfl_xor(s2r[m], 32);
    }
    if (lgp == 0) {
      part[(lm*4      + wave)*2 + 0] = s1r[0];
      part[(lm*4      + wave)*2 + 1] = s2r[0];
      part[((16+lm)*4 + wave)*2 + 0] = s1r[1];
      part[((16+lm)*4 + wave)*2 + 1] = s2r[1];
    }
    __syncthreads();
    if (tid < 32) {
      float s1 = 0.f, s2 = 0.f;
      #pragma unroll
      for (int w = 0; w < 4; ++w) { s1 += part[(tid*4+w)*2]; s2 += part[(tid*4+w)*2+1]; }
      float mu  = s1*(1.f/128.f);
      float var = (s2 - 128.f*mu*mu)*(1.f/127.f);
      red[tid*2]   = mu;
      red[tid*2+1] = 1.f/(sqrtf(var+LN_EPS)+LN_EPS);
    }
    __syncthreads();
    #pragma unroll
    for (int m = 0; m < 2; ++m) {
      int row = m*16 + lm;
      float mu = red[row*2], inv = red[row*2+1];
      #pragma unroll
      for (int n = 0; n < 2; ++n) {
        int col = (wave*2 + n)*16 + lgp*4;
        float4 g = *(const float4*)&gain0[col];
        float4 b = *(const float4*)&bias0[col];
        hn[m][n][0] = g.x*(x[m][n][0]-mu)*inv + b.x;
        hn[m][n][1] = g.y*(x[m][n][1]-mu)*inv + b.y;
        hn[m][n][2] = g.z*(x[m][n][2]-mu)*inv + b.z;
        hn[m][n][3] = g.w*(x[m][n][3]-mu)*inv + b.w;
        short4v p;
        p[0]=(short)f2bf(hn[m][n][0]); p[1]=(short)f2bf(hn[m][n][1]);
        p[2]=(short)f2bf(hn[m][n][2]); p[3]=(short)f2bf(hn[m][n][3]);
        *(short4v*)&At[row*136 + col] = p;
      }
    }
  }

  f32x4 acc1[2][8] = {};
  #pragma unroll
  for (int ks = 0; ks < 4; ++ks) {
    asm volatile("s_waitcnt vmcnt(0)" ::: "memory");
    __builtin_amdgcn_s_barrier();
    if (ks < 3) {
      #pragma unroll
      for (int p = 0; p < 8; ++p)
        gload16(Wi2 + (size_t)(ks+1)*16384 + (tid + p*256)*8,
                &Wst[((ks+1)&1)*16384 + (tid + p*256)*8]);
    } else {
      #pragma unroll
      for (int p = 0; p < 4; ++p)
        gload16(Wo2 + (size_t)(tid + p*256)*8, &Wst[(tid + p*256)*8]);
    }

    short8v a0 = *(const short8v*)&At[lm*136      + ks*32 + lgp*8];
    short8v a1 = *(const short8v*)&At[(16+lm)*136 + ks*32 + lgp*8];
    #pragma unroll
    for (int n = 0; n < 8; ++n) {
      short8v b = *(const short8v*)&Wst[(ks&1)*16384 + ((wave*8 + n)*64 + lane)*8];
      acc1[0][n] = __builtin_amdgcn_mfma_f32_16x16x32_bf16(b, a0, acc1[0][n], 0, 0, 0);
      acc1[1][n] = __builtin_amdgcn_mfma_f32_16x16x32_bf16(b, a1, acc1[1][n], 0, 0, 0);
    }
  }

  #pragma unroll
  for (int m = 0; m < 2; ++m) {
    int row = m*16 + lm;
    #pragma unroll
    for (int n = 0; n < 8; ++n) {
      int col = (wave*8 + n)*16 + lgp*4;
      float4 bv = *(const float4*)&bin[col];
      short4v p;
      p[0]=(short)f2bf(fmaxf(acc1[m][n][0] + bv.x, 0.f));
      p[1]=(short)f2bf(fmaxf(acc1[m][n][1] + bv.y, 0.f));
      p[2]=(short)f2bf(fmaxf(acc1[m][n][2] + bv.z, 0.f));
      p[3]=(short)f2bf(fmaxf(acc1[m][n][3] + bv.w, 0.f));
      *(short4v*)&Zs[row*520 + col] = p;
    }
  }

  f32x4 acc2[2][2] = {};
  #pragma unroll
  for (int ks2 = 0; ks2 < 8; ++ks2) {
    asm volatile("s_waitcnt vmcnt(0)" ::: "memory");
    __builtin_amdgcn_s_barrier();
    if (ks2 < 7) {
      #pragma unroll
      for (int p = 0; p < 4; ++p)
        gload16(Wo2 + (size_t)(ks2+1)*8192 + (tid + p*256)*8,
                &Wst[((ks2+1)&1)*8192 + (tid + p*256)*8]);
    }

    #pragma unroll
    for (int s = 0; s < 2; ++s) {
      int ks = ks2*2 + s;
      short8v a0 = *(const short8v*)&Zs[lm*520      + ks*32 + lgp*8];
      short8v a1 = *(const short8v*)&Zs[(16+lm)*520 + ks*32 + lgp*8];
      #pragma unroll
      for (int n = 0; n < 2; ++n) {
        short8v b = *(const short8v*)&Wst[(ks2&1)*8192 + s*4096 + ((wave*2 + n)*64 + lane)*8];
        acc2[0][n] = __builtin_amdgcn_mfma_f32_16x16x32_bf16(b, a0, acc2[0][n], 0, 0, 0);
        acc2[1][n] = __builtin_amdgcn_mfma_f32_16x16x32_bf16(b, a1, acc2[1][n], 0, 0, 0);
      }
    }
  }

  {
    f32x4 x[2][2];
    float s1r[2] = {0.f, 0.f}, s2r[2] = {0.f, 0.f};
    #pragma unroll
    for (int m = 0; m < 2; ++m) {
      #pragma unroll
      for (int n = 0; n < 2; ++n) {
        int col = (wave*2 + n)*16 + lgp*4;
        float4 bo = *(const float4*)&b_out[col];
        x[m][n][0] = acc2[m][n][0] + bo.x + hn[m][n][0];
        x[m][n][1] = acc2[m][n][1] + bo.y + hn[m][n][1];
        x[m][n][2] = acc2[m][n][2] + bo.z + hn[m][n][2];
        x[m][n][3] = acc2[m][n][3] + bo.w + hn[m][n][3];
        #pragma unroll
        for (int r = 0; r < 4; ++r) {
          s1r[m] += x[m][n][r];
          s2r[m] += x[m][n][r]*x[m][n][r];
        }
      }
    }
    #pragma unroll
    for (int m = 0; m < 2; ++m) {
      s1r[m] += __shfl_xor(s1r[m], 16); s2r[m] += __shfl_xor(s2r[m], 16);
      s1r[m] += __shfl_xor(s1r[m], 32); s2r[m] += __shfl_xor(s2r[m], 32);
    }
    if (lgp == 0) {
      part[(lm*4      + wave)*2 + 0] = s1r[0];
      part[(lm*4      + wave)*2 + 1] = s2r[0];
      part[((16+lm)*4 + wave)*2 + 0] = s1r[1];
      part[((16+lm)*4 + wave)*2 + 1] = s2r[1];
    }
    __syncthreads();
    if (tid < 32) {
      float s1 = 0.f, s2 = 0.f;
      #pragma unroll
      for (int w = 0; w < 4; ++w) { s1 += part[(tid*4+w)*2]; s2 += part[(tid*4+w)*2+1]; }
      float mu  = s1*(1.f/128.f);
      float var = (s2 - 128.f*mu*mu)*(1.f/127.f);
      red[tid*2]   = mu;
      red[tid*2+1] = 1.f/(sqrtf(var+LN_EPS)+LN_EPS);
    }
    __syncthreads();
    #pragma unroll
    for (int m = 0; m < 2; ++m) {
      int row = m*16 + lm;
      float mu = red[row*2], inv = red[row*2+1];
      float mv = mask_v[tok0 + row];
      #pragma unroll
      for (int n = 0; n < 2; ++n) {
        int col = (wave*2 + n)*16 + lgp*4;
        float4 g = *(const float4*)&gain1[col];
        float4 b = *(const float4*)&bias1[col];
        float4 y;
        y.x = mv*(g.x*(x[m][n][0]-mu)*inv + b.x);
        y.y = mv*(g.y*(x[m][n][1]-mu)*inv + b.y);
        y.z = mv*(g.z*(x[m][n][2]-mu)*inv + b.z);
        y.w = mv*(g.w*(x[m][n][3]-mu)*inv + b.w);
        *(float4*)&out[(size_t)(tok0+row)*TH + col] = y;
      }
    }
  }
}

// ---------------------------------------------------------------------------
extern "C" void kernel_launch(void* const* d_in, const int* in_sizes, int n_in,
                              void* d_out, int out_size, void* d_ws, size_t ws_size,
                              hipStream_t stream)
{
  const float* h_v         = (const float*)d_in[0];
  const float* h_e         = (const float*)d_in[1];
  const float* mask_v      = (const float*)d_in[2];
  const float* mask_attend = (const float*)d_in[3];
  const float* W_Q   = (const float*)d_in[4];
  const float* W_K   = (const float*)d_in[5];
  const float* W_V   = (const float*)d_in[6];
  const float* W_O   = (const float*)d_in[7];
  const float* gain0 = (const float*)d_in[8];
  const float* bias0 = (const float*)d_in[9];
  const float* gain1 = (const float*)d_in[10];
  const float* bias1 = (const float*)d_in[11];
  const float* W_in  = (const float*)d_in[12];
  const float* b_in  = (const float*)d_in[13];
  const float* W_out = (const float*)d_in[14];
  const float* b_out = (const float*)d_in[15];

  float* out = (float*)d_out;
  char* ws = (char*)d_ws;
  unsigned short* Wc2 = (unsigned short*)ws;               //  131,072 B
  unsigned short* Wq2 = (unsigned short*)(ws + 131072);    //   32,768 B
  unsigned short* Wp2 = (unsigned short*)(ws + 163840);    //   32,768 B
  unsigned short* Wi2 = (unsigned short*)(ws + 196608);    //  131,072 B
  unsigned short* Wo2 = (unsigned short*)(ws + 327680);    //  131,072 B
  float* ul = (float*)(ws + 458752);                       // 4,096,000 B

  conv_weights_kernel<<<896, 256, 0, stream>>>(W_K, W_V, W_Q, W_O, W_in, W_out,
                                               Wc2, Wq2, Wp2, Wi2, Wo2);
  kvattn_kernel<<<NTOK/4, 256, 0, stream>>>(h_e, Wc2, Wq2, h_v, mask_attend, ul);
  ffn_all_kernel<<<NTOK/32, 256, 0, stream>>>(ul, Wp2, h_v, gain0, bias0,
                                              Wi2, Wo2, b_in, b_out,
                                              gain1, bias1, mask_v, out);
}

// Round 14
// 88.600 us; speedup vs baseline: 1.0493x; 1.0493x over previous
//
#include <hip/hip_runtime.h>
#include <math.h>

#define TK 30
#define TH 128
#define TNIN 256
#define TDFF 512
#define NTOK 8000
#define ROWP 264   // KVs row stride in u16

typedef __attribute__((ext_vector_type(8))) short short8v;
typedef __attribute__((ext_vector_type(4))) short short4v;
typedef __attribute__((ext_vector_type(4))) float f32x4;

constexpr float LN_EPS = 1e-6f;
constexpr float NEG_INF = -3.402823466e38f;
constexpr float INV_SQRT_D = 0.17677669529663687f;  // 1/sqrt(32)

static __device__ __forceinline__ unsigned short f2bf(float f) {
  unsigned u = __float_as_uint(f);
  u = u + 0x7fffu + ((u >> 16) & 1u);
  return (unsigned short)(u >> 16);
}
static __device__ __forceinline__ float bf2f(unsigned short s) {
  return __uint_as_float(((unsigned)s) << 16);
}
static __device__ __forceinline__ void gload16(const void* gsrc, void* ldst) {
  __builtin_amdgcn_global_load_lds(
      (const __attribute__((address_space(1))) unsigned int*)gsrc,
      (__attribute__((address_space(3))) unsigned int*)ldst, 16, 0, 0);
}

// ---------------------------------------------------------------------------
// K0: weight prep (verbatim R11, verified). Frag-linear bf16:
//   elem ((ks*NF + n)*64 + lane)*8 + j = W[n*16+(lane&15)][ks*32+(lane>>4)*8+j]
// ---------------------------------------------------------------------------
__global__ void conv_weights_kernel(const float* __restrict__ W_K,
                                    const float* __restrict__ W_V,
                                    const float* __restrict__ W_Q,
                                    const float* __restrict__ W_O,
                                    const float* __restrict__ W_in,
                                    const float* __restrict__ W_out,
                                    unsigned short* __restrict__ Wc2,
                                    unsigned short* __restrict__ Wq2,
                                    unsigned short* __restrict__ Wp2,
                                    unsigned short* __restrict__ Wi2,
                                    unsigned short* __restrict__ Wo2)
{
  int idx = blockIdx.x * 256 + threadIdx.x;   // 0..229375
  if (idx < 65536) {
    int e = idx >> 3, j = idx & 7;
    int kk = e >> 10, n = (e >> 6) & 15, lane = e & 63;
    int r = n*16 + (lane & 15);
    int c = kk*32 + (lane >> 4)*8 + j;
    float v = (r < TH) ? W_K[(size_t)r*TNIN + c] : W_V[(size_t)(r-TH)*TNIN + c];
    Wc2[idx] = f2bf(v);
  } else if (idx < 81920) {
    int i2 = idx - 65536;
    int e = i2 >> 3, j = i2 & 7;
    int kk = e >> 9, n = (e >> 6) & 7, lane = e & 63;
    int r = n*16 + (lane & 15);
    int c = kk*32 + (lane >> 4)*8 + j;
    Wq2[i2] = f2bf(W_Q[(size_t)r*TH + c]);
  } else if (idx < 98304) {
    int ip = idx - 81920;
    int e = ip >> 3, j = ip & 7;
    int kk = e >> 9, n = (e >> 6) & 7, lane = e & 63;
    int r = n*16 + (lane & 15);
    int c = kk*32 + (lane >> 4)*8 + j;
    Wp2[ip] = f2bf(W_O[(size_t)r*TH + c]);
  } else if (idx < 163840) {
    int i3 = idx - 98304;
    int e = i3 >> 3, j = i3 & 7;
    int ks = e >> 11, n = (e >> 6) & 31, lane = e & 63;
    int r = n*16 + (lane & 15);
    int c = ks*32 + (lane >> 4)*8 + j;
    Wi2[i3] = f2bf(W_in[(size_t)r*TH + c]);
  } else {
    int i4 = idx - 163840;
    int e = i4 >> 3, j = i4 & 7;
    int ks = e >> 9, n = (e >> 6) & 7, lane = e & 63;
    int r = n*16 + (lane & 15);
    int c = ks*32 + (lane >> 4)*8 + j;
    Wo2[i4] = f2bf(W_out[(size_t)r*TDFF + c]);
  }
}

// ---------------------------------------------------------------------------
// K1: R14 — 2-token blocks (64 A-rows), 512 thr, 3 blocks/CU (24 waves/CU).
// Wave (mh=w>>2, nq=w&3) owns M32 x N64: acc[2][4] = 32 VGPR.
// B double-buffered (dist-1, L2); A reg-staged triple (dist-2.5, HBM).
// LDS 46 KB: Bl[2][8192]us | Al[2][64][40]us | hvp | qvp | att; KVs[64][264]
// overlays Bl+Al-head after the GEMM. All math verbatim-verified (R11).
// ---------------------------------------------------------------------------
__global__ __launch_bounds__(512, 6) void kvattn_kernel(
    const float* __restrict__ A, const unsigned short* __restrict__ Wc2,
    const unsigned short* __restrict__ Wq2, const float* __restrict__ h_v,
    const float* __restrict__ mask_attend, float* __restrict__ ul)
{
  const int tid  = threadIdx.x;
  const int wave = tid >> 6;
  const int lane = tid & 63;
  const int lm   = lane & 15;
  const int lgp  = lane >> 4;
  const int mh   = wave >> 2;   // 0..1  (M-half)
  const int nq   = wave & 3;    // 0..3  (N-quarter)
  const int bn0  = blockIdx.x * 2;

  __shared__ __align__(16) char smem[46080];
  unsigned short* Bl  = (unsigned short*)smem;           // [2][8192]   0..32768
  unsigned short* Al  = (unsigned short*)(smem + 32768); // [2][64][40] ..43008
  unsigned short* KVs = (unsigned short*)smem;           // [64][264] overlay 0..33792
  float* hvp = (float*)(smem + 43008);                   // [2][128]
  float* qvp = (float*)(smem + 44032);                   // [2][128]
  float* att = (float*)(smem + 45056);                   // [2][4][32]

  // ---- prologue extras: h_v to LDS ----
  if (tid < 64) {
    int tok = tid >> 5, q = tid & 31;
    *(float4*)&hvp[tok*128 + q*4] = *(const float4*)&h_v[(size_t)(bn0 + tok)*TH + q*4];
  }

  // A staging: thread -> row (tid>>3), 4-f32 col group (tid&7)
  const int rowa = tid >> 3, cga = tid & 7;
  const int rowc = (rowa > 59) ? 59 : rowa;
  const float* aptr = A + ((size_t)blockIdx.x*60 + rowc)*TNIN + cga*4;

  #define ISSUE_B(K)                                                               \
    { gload16(Wc2 + (size_t)(K)*8192 + tid*8,       &Bl[((K)&1)*8192 + tid*8]);    \
      gload16(Wc2 + (size_t)(K)*8192 + (tid+512)*8, &Bl[((K)&1)*8192 + (tid+512)*8]); }

  #define LOAD_RA(S, K)  { ra[S] = *(const float4*)(aptr + (K)*32); }

  #define WRITE_A(K, S)                                                     \
    { short4v w;                                                            \
      w[0]=(short)f2bf(ra[S].x); w[1]=(short)f2bf(ra[S].y);                 \
      w[2]=(short)f2bf(ra[S].z); w[3]=(short)f2bf(ra[S].w);                 \
      *(short4v*)&Al[(((K)&1)*64 + rowa)*40 + cga*4] = w; }

  float4 ra[3];
  f32x4 acc[2][4] = {};

  // prologue: rA(0); B(0); rA(1); rA(2); write A(0)
  LOAD_RA(0, 0);
  ISSUE_B(0);
  LOAD_RA(1, 1);
  LOAD_RA(2, 2);
  WRITE_A(0, 0);   // auto-waits rA0 (drains hvp too, in-order)

  #pragma unroll
  for (int k = 0; k < 8; ++k) {
    // audit: outstanding at wait = B(k)[2] + rA(k+1),rA(k+2)[<=2]
    if      (k <= 5) asm volatile("s_waitcnt vmcnt(2)" ::: "memory");
    else if (k == 6) asm volatile("s_waitcnt vmcnt(1)" ::: "memory");
    else             asm volatile("s_waitcnt vmcnt(0)" ::: "memory");
    __builtin_amdgcn_s_barrier();

    if (k < 7) ISSUE_B(k+1);          // -> Bl[(k+1)&1], last read step k-1 (WAR ok)
    if (k < 5) LOAD_RA(k%3, k+3);     // rA dist ~2.5 steps (HBM covered)

    short8v af[2];
    #pragma unroll
    for (int m = 0; m < 2; ++m)
      af[m] = *(const short8v*)&Al[((k&1)*64 + mh*32 + m*16 + lm)*40 + lgp*8];

    __builtin_amdgcn_s_setprio(1);
    #pragma unroll
    for (int n = 0; n < 4; ++n) {
      short8v b = *(const short8v*)&Bl[(k&1)*8192 + ((nq*4 + n)*64 + lane)*8];
      #pragma unroll
      for (int m = 0; m < 2; ++m)
        acc[m][n] = __builtin_amdgcn_mfma_f32_16x16x32_bf16(b, af[m], acc[m][n], 0, 0, 0);
    }
    __builtin_amdgcn_s_setprio(0);

    if (k < 7) WRITE_A(k+1, (k+1)%3);
  }
  #undef ISSUE_B
  #undef LOAD_RA
  #undef WRITE_A

  __syncthreads();   // all Bl/Al reads done before KVs overlay

  // ---- C writeout (verified swapped-operand mapping) ----
  #pragma unroll
  for (int m = 0; m < 2; ++m) {
    int row = mh*32 + m*16 + lm;
    #pragma unroll
    for (int n = 0; n < 4; ++n) {
      int col = nq*64 + n*16 + lgp*4;
      short4v p;
      p[0]=(short)f2bf(acc[m][n][0]); p[1]=(short)f2bf(acc[m][n][1]);
      p[2]=(short)f2bf(acc[m][n][2]); p[3]=(short)f2bf(acc[m][n][3]);
      *(short4v*)&KVs[row*ROWP + col] = p;
    }
  }

  // ---- Q = h_v @ W_Q^T (acc dead; wave covers col-frag `wave`) ----
  // D[row=lm (token, lm<2 valid)][col = wave*16 + lgp*4 + r]
  {
    f32x4 qacc = {};
    const int tokc = (lm < 2) ? lm : 1;
    #pragma unroll
    for (int ks = 0; ks < 4; ++ks) {
      short8v wq = *(const short8v*)(Wq2 + ((size_t)(ks*8 + wave)*64 + lane)*8);
      const float* hp = hvp + tokc*128 + ks*32 + lgp*8;
      float4 lo = *(const float4*)hp;
      float4 hi = *(const float4*)(hp + 4);
      short8v ha;
      ha[0]=(short)f2bf(lo.x); ha[1]=(short)f2bf(lo.y);
      ha[2]=(short)f2bf(lo.z); ha[3]=(short)f2bf(lo.w);
      ha[4]=(short)f2bf(hi.x); ha[5]=(short)f2bf(hi.y);
      ha[6]=(short)f2bf(hi.z); ha[7]=(short)f2bf(hi.w);
      qacc = __builtin_amdgcn_mfma_f32_16x16x32_bf16(wq, ha, qacc, 0, 0, 0);
    }
    if (lm < 2) *(f32x4*)&qvp[lm*128 + wave*16 + lgp*4] = qacc;
  }
  __syncthreads();   // KVs + qvp visible

  // ---- logits + masked softmax (256 active: tok = tid>>7, 2 tokens) ----
  if (tid < 256) {
    int tok = tid >> 7, h = (tid >> 5) & 3, k = tid & 31;
    int gtok = bn0 + tok;
    float s = 0.f;
    float ma = 0.f;
    if (k < TK) {
      const float* qp = &qvp[tok*128 + h*32];
      const unsigned short* kp = &KVs[(tok*TK + k)*ROWP + h*32];
      #pragma unroll
      for (int j = 0; j < 4; ++j) {
        short8v kf = *(const short8v*)(kp + j*8);
        float4 qa = *(const float4*)(qp + j*8);
        float4 qb = *(const float4*)(qp + j*8 + 4);
        s += qa.x*bf2f((unsigned short)kf[0]) + qa.y*bf2f((unsigned short)kf[1])
           + qa.z*bf2f((unsigned short)kf[2]) + qa.w*bf2f((unsigned short)kf[3])
           + qb.x*bf2f((unsigned short)kf[4]) + qb.y*bf2f((unsigned short)kf[5])
           + qb.z*bf2f((unsigned short)kf[6]) + qb.w*bf2f((unsigned short)kf[7]);
      }
      ma = mask_attend[(size_t)gtok*TK + k];
    }
    bool ok = (k < TK) && (ma > 0.f);
    float val = ok ? s * INV_SQRT_D : NEG_INF;
    float mm = val;
    #pragma unroll
    for (int d = 16; d >= 1; d >>= 1) mm = fmaxf(mm, __shfl_xor(mm, d, 32));
    float e = ok ? expf(val - mm) : 0.f;
    float ss = e;
    #pragma unroll
    for (int d = 16; d >= 1; d >>= 1) ss += __shfl_xor(ss, d, 32);
    att[(tok*4 + h)*32 + k] = e / ss;
  }
  __syncthreads();

  // ---- PV (256 active) ----
  if (tid < 256) {
    int tok = tid >> 7, c = tid & 127;
    int gtok = bn0 + tok;
    const float* ar = &att[(tok*4 + (c >> 5))*32];
    const unsigned short* vb = &KVs[(tok*TK)*ROWP + TH + c];
    float u = 0.f;
    #pragma unroll
    for (int k = 0; k < TK; ++k)
      u += ar[k] * bf2f(vb[k*ROWP]);
    ul[(size_t)gtok*TH + c] = u;
  }
}

// ---------------------------------------------------------------------------
// K2: ffn_all (verbatim R11, verified).
// ---------------------------------------------------------------------------
__global__ __launch_bounds__(256) void ffn_all_kernel(
    const float* __restrict__ ul, const unsigned short* __restrict__ Wp2,
    const float* __restrict__ h_v,
    const float* __restrict__ gain0, const float* __restrict__ bias0,
    const unsigned short* __restrict__ Wi2, const unsigned short* __restrict__ Wo2,
    const float* __restrict__ b_in, const float* __restrict__ b_out,
    const float* __restrict__ gain1, const float* __restrict__ bias1,
    const float* __restrict__ mask_v, float* __restrict__ out)
{
  const int tid  = threadIdx.x;
  const int tok0 = blockIdx.x * 32;
  const int wave = tid >> 6;
  const int lane = tid & 63;
  const int lm   = lane & 15;
  const int lgp  = lane >> 4;

  __shared__ __align__(16) char smem[143616];
  unsigned short* Wp  = (unsigned short*)smem;            // 32 KB
  unsigned short* Wst = (unsigned short*)(smem + 32768);  // 64 KB dbuf
  unsigned short* At  = (unsigned short*)(smem + 98304);  // [32][136]
  unsigned short* Zs  = (unsigned short*)(smem + 107008); // [32][520]
  float* bin  = (float*)(smem + 140288);
  float* part = (float*)(smem + 142336);
  float* red  = (float*)(smem + 143360);

  for (int t = tid; t < 1024; t += 256) {
    int row = t >> 5, q = t & 31;
    float4 v = *(const float4*)&ul[(size_t)(tok0+row)*TH + q*4];
    short4v w;
    w[0]=(short)f2bf(v.x); w[1]=(short)f2bf(v.y);
    w[2]=(short)f2bf(v.z); w[3]=(short)f2bf(v.w);
    *(short4v*)&At[row*136 + q*4] = w;
  }
  if (tid < 128) *(float4*)&bin[tid*4] = *(const float4*)&b_in[tid*4];
  #pragma unroll
  for (int p = 0; p < 8; ++p)
    gload16(Wp2 + (size_t)(tid + p*256)*8, &Wp[(tid + p*256)*8]);
  #pragma unroll
  for (int p = 0; p < 8; ++p)
    gload16(Wi2 + (size_t)(tid + p*256)*8, &Wst[(tid + p*256)*8]);

  asm volatile("s_waitcnt vmcnt(8)" ::: "memory");
  __syncthreads();

  f32x4 acco[2][2] = {};
  #pragma unroll
  for (int ks = 0; ks < 4; ++ks) {
    short8v a0 = *(const short8v*)&At[lm*136      + ks*32 + lgp*8];
    short8v a1 = *(const short8v*)&At[(16+lm)*136 + ks*32 + lgp*8];
    #pragma unroll
    for (int n = 0; n < 2; ++n) {
      short8v b = *(const short8v*)&Wp[((size_t)(ks*8 + wave*2 + n)*64 + lane)*8];
      acco[0][n] = __builtin_amdgcn_mfma_f32_16x16x32_bf16(b, a0, acco[0][n], 0, 0, 0);
      acco[1][n] = __builtin_amdgcn_mfma_f32_16x16x32_bf16(b, a1, acco[1][n], 0, 0, 0);
    }
  }

  f32x4 hn[2][2];
  {
    f32x4 x[2][2];
    float s1r[2] = {0.f, 0.f}, s2r[2] = {0.f, 0.f};
    #pragma unroll
    for (int m = 0; m < 2; ++m) {
      int row = m*16 + lm;
      #pragma unroll
      for (int n = 0; n < 2; ++n) {
        int col = (wave*2 + n)*16 + lgp*4;
        float4 hv = *(const float4*)&h_v[(size_t)(tok0+row)*TH + col];
        x[m][n][0] = acco[m][n][0] + hv.x;
        x[m][n][1] = acco[m][n][1] + hv.y;
        x[m][n][2] = acco[m][n][2] + hv.z;
        x[m][n][3] = acco[m][n][3] + hv.w;
        #pragma unroll
        for (int r = 0; r < 4; ++r) {
          s1r[m] += x[m][n][r];
          s2r[m] += x[m][n][r]*x[m][n][r];
        }
      }
    }
    #pragma unroll
    for (int m = 0; m < 2; ++m) {
      s1r[m] += __shfl_xor(s1r[m], 16); s2r[m] += __shfl_xor(s2r[m], 16);
      s1r[m] += __shfl_xor(s1r[m], 32); s2r[m] += __shfl_xor(s2r[m], 32);
    }
    if (lgp == 0) {
      part[(lm*4      + wave)*2 + 0] = s1r[0];
      part[(lm*4      + wave)*2 + 1] = s2r[0];
      part[((16+lm)*4 + wave)*2 + 0] = s1r[1];
      part[((16+lm)*4 + wave)*2 + 1] = s2r[1];
    }
    __syncthreads();
    if (tid < 32) {
      float s1 = 0.f, s2 = 0.f;
      #pragma unroll
      for (int w = 0; w < 4; ++w) { s1 += part[(tid*4+w)*2]; s2 += part[(tid*4+w)*2+1]; }
      float mu  = s1*(1.f/128.f);
      float var = (s2 - 128.f*mu*mu)*(1.f/127.f);
      red[tid*2]   = mu;
      red[tid*2+1] = 1.f/(sqrtf(var+LN_EPS)+LN_EPS);
    }
    __syncthreads();
    #pragma unroll
    for (int m = 0; m < 2; ++m) {
      int row = m*16 + lm;
      float mu = red[row*2], inv = red[row*2+1];
      #pragma unroll
      for (int n = 0; n < 2; ++n) {
        int col = (wave*2 + n)*16 + lgp*4;
        float4 g = *(const float4*)&gain0[col];
        float4 b = *(const float4*)&bias0[col];
        hn[m][n][0] = g.x*(x[m][n][0]-mu)*inv + b.x;
        hn[m][n][1] = g.y*(x[m][n][1]-mu)*inv + b.y;
        hn[m][n][2] = g.z*(x[m][n][2]-mu)*inv + b.z;
        hn[m][n][3] = g.w*(x[m][n][3]-mu)*inv + b.w;
        short4v p;
        p[0]=(short)f2bf(hn[m][n][0]); p[1]=(short)f2bf(hn[m][n][1]);
        p[2]=(short)f2bf(hn[m][n][2]); p[3]=(short)f2bf(hn[m][n][3]);
        *(short4v*)&At[row*136 + col] = p;
      }
    }
  }

  f32x4 acc1[2][8] = {};
  #pragma unroll
  for (int ks = 0; ks < 4; ++ks) {
    asm volatile("s_waitcnt vmcnt(0)" ::: "memory");
    __builtin_amdgcn_s_barrier();
    if (ks < 3) {
      #pragma unroll
      for (int p = 0; p < 8; ++p)
        gload16(Wi2 + (size_t)(ks+1)*16384 + (tid + p*256)*8,
                &Wst[((ks+1)&1)*16384 + (tid + p*256)*8]);
    } else {
      #pragma unroll
      for (int p = 0; p < 4; ++p)
        gload16(Wo2 + (size_t)(tid + p*256)*8, &Wst[(tid + p*256)*8]);
    }

    short8v a0 = *(const short8v*)&At[lm*136      + ks*32 + lgp*8];
    short8v a1 = *(const short8v*)&At[(16+lm)*136 + ks*32 + lgp*8];
    #pragma unroll
    for (int n = 0; n < 8; ++n) {
      short8v b = *(const short8v*)&Wst[(ks&1)*16384 + ((wave*8 + n)*64 + lane)*8];
      acc1[0][n] = __builtin_amdgcn_mfma_f32_16x16x32_bf16(b, a0, acc1[0][n], 0, 0, 0);
      acc1[1][n] = __builtin_amdgcn_mfma_f32_16x16x32_bf16(b, a1, acc1[1][n], 0, 0, 0);
    }
  }

  #pragma unroll
  for (int m = 0; m < 2; ++m) {
    int row = m*16 + lm;
    #pragma unroll
    for (int n = 0; n < 8; ++n) {
      int col = (wave*8 + n)*16 + lgp*4;
      float4 bv = *(const float4*)&bin[col];
      short4v p;
      p[0]=(short)f2bf(fmaxf(acc1[m][n][0] + bv.x, 0.f));
      p[1]=(short)f2bf(fmaxf(acc1[m][n][1] + bv.y, 0.f));
      p[2]=(short)f2bf(fmaxf(acc1[m][n][2] + bv.z, 0.f));
      p[3]=(short)f2bf(fmaxf(acc1[m][n][3] + bv.w, 0.f));
      *(short4v*)&Zs[row*520 + col] = p;
    }
  }

  f32x4 acc2[2][2] = {};
  #pragma unroll
  for (int ks2 = 0; ks2 < 8; ++ks2) {
    asm volatile("s_waitcnt vmcnt(0)" ::: "memory");
    __builtin_amdgcn_s_barrier();
    if (ks2 < 7) {
      #pragma unroll
      for (int p = 0; p < 4; ++p)
        gload16(Wo2 + (size_t)(ks2+1)*8192 + (tid + p*256)*8,
                &Wst[((ks2+1)&1)*8192 + (tid + p*256)*8]);
    }

    #pragma unroll
    for (int s = 0; s < 2; ++s) {
      int ks = ks2*2 + s;
      short8v a0 = *(const short8v*)&Zs[lm*520      + ks*32 + lgp*8];
      short8v a1 = *(const short8v*)&Zs[(16+lm)*520 + ks*32 + lgp*8];
      #pragma unroll
      for (int n = 0; n < 2; ++n) {
        short8v b = *(const short8v*)&Wst[(ks2&1)*8192 + s*4096 + ((wave*2 + n)*64 + lane)*8];
        acc2[0][n] = __builtin_amdgcn_mfma_f32_16x16x32_bf16(b, a0, acc2[0][n], 0, 0, 0);
        acc2[1][n] = __builtin_amdgcn_mfma_f32_16x16x32_bf16(b, a1, acc2[1][n], 0, 0, 0);
      }
    }
  }

  {
    f32x4 x[2][2];
    float s1r[2] = {0.f, 0.f}, s2r[2] = {0.f, 0.f};
    #pragma unroll
    for (int m = 0; m < 2; ++m) {
      #pragma unroll
      for (int n = 0; n < 2; ++n) {
        int col = (wave*2 + n)*16 + lgp*4;
        float4 bo = *(const float4*)&b_out[col];
        x[m][n][0] = acc2[m][n][0] + bo.x + hn[m][n][0];
        x[m][n][1] = acc2[m][n][1] + bo.y + hn[m][n][1];
        x[m][n][2] = acc2[m][n][2] + bo.z + hn[m][n][2];
        x[m][n][3] = acc2[m][n][3] + bo.w + hn[m][n][3];
        #pragma unroll
        for (int r = 0; r < 4; ++r) {
          s1r[m] += x[m][n][r];
          s2r[m] += x[m][n][r]*x[m][n][r];
        }
      }
    }
    #pragma unroll
    for (int m = 0; m < 2; ++m) {
      s1r[m] += __shfl_xor(s1r[m], 16); s2r[m] += __shfl_xor(s2r[m], 16);
      s1r[m] += __shfl_xor(s1r[m], 32); s2r[m] += __shfl_xor(s2r[m], 32);
    }
    if (lgp == 0) {
      part[(lm*4      + wave)*2 + 0] = s1r[0];
      part[(lm*4      + wave)*2 + 1] = s2r[0];
      part[((16+lm)*4 + wave)*2 + 0] = s1r[1];
      part[((16+lm)*4 + wave)*2 + 1] = s2r[1];
    }
    __syncthreads();
    if (tid < 32) {
      float s1 = 0.f, s2 = 0.f;
      #pragma unroll
      for (int w = 0; w < 4; ++w) { s1 += part[(tid*4+w)*2]; s2 += part[(tid*4+w)*2+1]; }
      float mu  = s1*(1.f/128.f);
      float var = (s2 - 128.f*mu*mu)*(1.f/127.f);
      red[tid*2]   = mu;
      red[tid*2+1] = 1.f/(sqrtf(var+LN_EPS)+LN_EPS);
    }
    __syncthreads();
    #pragma unroll
    for (int m = 0; m < 2; ++m) {
      int row = m*16 + lm;
      float mu = red[row*2], inv = red[row*2+1];
      float mv = mask_v[tok0 + row];
      #pragma unroll
      for (int n = 0; n < 2; ++n) {
        int col = (wave*2 + n)*16 + lgp*4;
        float4 g = *(const float4*)&gain1[col];
        float4 b = *(const float4*)&bias1[col];
        float4 y;
        y.x = mv*(g.x*(x[m][n][0]-mu)*inv + b.x);
        y.y = mv*(g.y*(x[m][n][1]-mu)*inv + b.y);
        y.z = mv*(g.z*(x[m][n][2]-mu)*inv + b.z);
        y.w = mv*(g.w*(x[m][n][3]-mu)*inv + b.w);
        *(float4*)&out[(size_t)(tok0+row)*TH + col] = y;
      }
    }
  }
}

// ---------------------------------------------------------------------------
extern "C" void kernel_launch(void* const* d_in, const int* in_sizes, int n_in,
                              void* d_out, int out_size, void* d_ws, size_t ws_size,
                              hipStream_t stream)
{
  const float* h_v         = (const float*)d_in[0];
  const float* h_e         = (const float*)d_in[1];
  const float* mask_v      = (const float*)d_in[2];
  const float* mask_attend = (const float*)d_in[3];
  const float* W_Q   = (const float*)d_in[4];
  const float* W_K   = (const float*)d_in[5];
  const float* W_V   = (const float*)d_in[6];
  const float* W_O   = (const float*)d_in[7];
  const float* gain0 = (const float*)d_in[8];
  const float* bias0 = (const float*)d_in[9];
  const float* gain1 = (const float*)d_in[10];
  const float* bias1 = (const float*)d_in[11];
  const float* W_in  = (const float*)d_in[12];
  const float* b_in  = (const float*)d_in[13];
  const float* W_out = (const float*)d_in[14];
  const float* b_out = (const float*)d_in[15];

  float* out = (float*)d_out;
  char* ws = (char*)d_ws;
  unsigned short* Wc2 = (unsigned short*)ws;               //  131,072 B
  unsigned short* Wq2 = (unsigned short*)(ws + 131072);    //   32,768 B
  unsigned short* Wp2 = (unsigned short*)(ws + 163840);    //   32,768 B
  unsigned short* Wi2 = (unsigned short*)(ws + 196608);    //  131,072 B
  unsigned short* Wo2 = (unsigned short*)(ws + 327680);    //  131,072 B
  float* ul = (float*)(ws + 458752);                       // 4,096,000 B

  conv_weights_kernel<<<896, 256, 0, stream>>>(W_K, W_V, W_Q, W_O, W_in, W_out,
                                               Wc2, Wq2, Wp2, Wi2, Wo2);
  kvattn_kernel<<<NTOK/2, 512, 0, stream>>>(h_e, Wc2, Wq2, h_v, mask_attend, ul);
  ffn_all_kernel<<<NTOK/32, 256, 0, stream>>>(ul, Wp2, h_v, gain0, bias0,
                                              Wi2, Wo2, b_in, b_out,
                                              gain1, bias1, mask_v, out);
}

// Round 15
// 85.835 us; speedup vs baseline: 1.0831x; 1.0322x over previous
//
#include <hip/hip_runtime.h>
#include <math.h>

#define TK 30
#define TH 128
#define TNIN 256
#define TDFF 512
#define NTOK 8000
#define ROWP 264   // Ab/KVs row stride in u16

typedef __attribute__((ext_vector_type(8))) short short8v;
typedef __attribute__((ext_vector_type(4))) short short4v;
typedef __attribute__((ext_vector_type(4))) float f32x4;

constexpr float LN_EPS = 1e-6f;
constexpr float NEG_INF = -3.402823466e38f;
constexpr float INV_SQRT_D = 0.17677669529663687f;  // 1/sqrt(32)

static __device__ __forceinline__ unsigned short f2bf(float f) {
  unsigned u = __float_as_uint(f);
  u = u + 0x7fffu + ((u >> 16) & 1u);
  return (unsigned short)(u >> 16);
}
static __device__ __forceinline__ float bf2f(unsigned short s) {
  return __uint_as_float(((unsigned)s) << 16);
}
static __device__ __forceinline__ void gload16(const void* gsrc, void* ldst) {
  __builtin_amdgcn_global_load_lds(
      (const __attribute__((address_space(1))) unsigned int*)gsrc,
      (__attribute__((address_space(3))) unsigned int*)ldst, 16, 0, 0);
}

// ---------------------------------------------------------------------------
// K0: weight prep (verbatim R11, verified). Frag-linear bf16:
//   elem ((ks*NF + n)*64 + lane)*8 + j = W[n*16+(lane&15)][ks*32+(lane>>4)*8+j]
// ---------------------------------------------------------------------------
__global__ void conv_weights_kernel(const float* __restrict__ W_K,
                                    const float* __restrict__ W_V,
                                    const float* __restrict__ W_Q,
                                    const float* __restrict__ W_O,
                                    const float* __restrict__ W_in,
                                    const float* __restrict__ W_out,
                                    unsigned short* __restrict__ Wc2,
                                    unsigned short* __restrict__ Wq2,
                                    unsigned short* __restrict__ Wp2,
                                    unsigned short* __restrict__ Wi2,
                                    unsigned short* __restrict__ Wo2)
{
  int idx = blockIdx.x * 256 + threadIdx.x;   // 0..229375
  if (idx < 65536) {
    int e = idx >> 3, j = idx & 7;
    int kk = e >> 10, n = (e >> 6) & 15, lane = e & 63;
    int r = n*16 + (lane & 15);
    int c = kk*32 + (lane >> 4)*8 + j;
    float v = (r < TH) ? W_K[(size_t)r*TNIN + c] : W_V[(size_t)(r-TH)*TNIN + c];
    Wc2[idx] = f2bf(v);
  } else if (idx < 81920) {
    int i2 = idx - 65536;
    int e = i2 >> 3, j = i2 & 7;
    int kk = e >> 9, n = (e >> 6) & 7, lane = e & 63;
    int r = n*16 + (lane & 15);
    int c = kk*32 + (lane >> 4)*8 + j;
    Wq2[i2] = f2bf(W_Q[(size_t)r*TH + c]);
  } else if (idx < 98304) {
    int ip = idx - 81920;
    int e = ip >> 3, j = ip & 7;
    int kk = e >> 9, n = (e >> 6) & 7, lane = e & 63;
    int r = n*16 + (lane & 15);
    int c = kk*32 + (lane >> 4)*8 + j;
    Wp2[ip] = f2bf(W_O[(size_t)r*TH + c]);
  } else if (idx < 163840) {
    int i3 = idx - 98304;
    int e = i3 >> 3, j = i3 & 7;
    int ks = e >> 11, n = (e >> 6) & 31, lane = e & 63;
    int r = n*16 + (lane & 15);
    int c = ks*32 + (lane >> 4)*8 + j;
    Wi2[i3] = f2bf(W_in[(size_t)r*TH + c]);
  } else {
    int i4 = idx - 163840;
    int e = i4 >> 3, j = i4 & 7;
    int ks = e >> 9, n = (e >> 6) & 7, lane = e & 63;
    int r = n*16 + (lane & 15);
    int c = ks*32 + (lane >> 4)*8 + j;
    Wo2[i4] = f2bf(W_out[(size_t)r*TDFF + c]);
  }
}

// ---------------------------------------------------------------------------
// K1: R15 — BARRIER-FREE K-loop.
// Stage whole A-tile bf16 in LDS once (1 barrier); B fragments load straight
// from L2-resident Wc2 into a register double-buffer; K-loop has ZERO syncs,
// so the 8 waves free-run (no lockstep) and 16 waves/CU hide latency.
// Tail (C->KVs overlay, Q-MFMA, softmax, PV) verbatim R11.
// ---------------------------------------------------------------------------
__global__ __launch_bounds__(512, 4) void kvattn_kernel(
    const float* __restrict__ A, const unsigned short* __restrict__ Wc2,
    const unsigned short* __restrict__ Wq2, const float* __restrict__ h_v,
    const float* __restrict__ mask_attend, float* __restrict__ ul)
{
  const int tid  = threadIdx.x;
  const int wave = tid >> 6;
  const int lane = tid & 63;
  const int lm   = lane & 15;
  const int lgp  = lane >> 4;
  const int mh   = wave >> 2;   // 0..1
  const int nq   = wave & 3;    // 0..3
  const int bn0  = blockIdx.x * 4;

  __shared__ __align__(16) char smem[73728];
  unsigned short* Ab  = (unsigned short*)smem;   // [128][264] bf16; KVs overlay
  unsigned short* KVs = (unsigned short*)smem;
  float* hvp = (float*)(smem + 67584);           // [4][128]
  float* qvp = (float*)(smem + 69632);           // [4][128]
  float* att = (float*)(smem + 71680);           // [4][4][32]

  // ---- stage h_v ----
  if (tid < 128) {
    int tok = tid >> 5, q = tid & 31;
    *(float4*)&hvp[tok*128 + q*4] = *(const float4*)&h_v[(size_t)(bn0 + tok)*TH + q*4];
  }

  // ---- stage whole A-tile as bf16 (rows 120..127 clamp-junk) ----
  #pragma unroll
  for (int i = 0; i < 16; ++i) {
    int idx = tid + i*512;              // 0..8191
    int row = idx >> 6, cg = idx & 63;
    int rowc = (row > 119) ? 119 : row;
    float4 v = *(const float4*)&A[((size_t)blockIdx.x*120 + rowc)*TNIN + cg*4];
    short4v w;
    w[0]=(short)f2bf(v.x); w[1]=(short)f2bf(v.y);
    w[2]=(short)f2bf(v.z); w[3]=(short)f2bf(v.w);
    *(short4v*)&Ab[row*ROWP + cg*4] = w;
  }
  __syncthreads();   // barrier 1: Ab + hvp visible

  // ---- K-loop: NO BARRIERS. B frags from global (L2) reg-dbuf. ----
  f32x4 acc[4][4] = {};
  short8v bcur[4], bnxt[4];
  #pragma unroll
  for (int n = 0; n < 4; ++n)
    bcur[n] = *(const short8v*)(Wc2 + ((size_t)(nq*4 + n)*64 + lane)*8);

  #pragma unroll
  for (int k = 0; k < 8; ++k) {
    if (k < 7) {
      #pragma unroll
      for (int n = 0; n < 4; ++n)
        bnxt[n] = *(const short8v*)(Wc2 + ((size_t)((k+1)*16 + nq*4 + n)*64 + lane)*8);
    }
    #pragma unroll
    for (int m = 0; m < 4; ++m) {
      short8v a = *(const short8v*)&Ab[(mh*64 + m*16 + lm)*ROWP + k*32 + lgp*8];
      #pragma unroll
      for (int n = 0; n < 4; ++n)
        acc[m][n] = __builtin_amdgcn_mfma_f32_16x16x32_bf16(bcur[n], a, acc[m][n], 0, 0, 0);
    }
    if (k < 7) {
      #pragma unroll
      for (int n = 0; n < 4; ++n) bcur[n] = bnxt[n];
    }
  }

  // ---- Q = h_v @ W_Q^T (before the overlay barrier; reads hvp only) ----
  {
    f32x4 qacc = {};
    const int tokc = (lm < 4) ? lm : 3;
    #pragma unroll
    for (int ks = 0; ks < 4; ++ks) {
      short8v wq = *(const short8v*)(Wq2 + ((size_t)(ks*8 + wave)*64 + lane)*8);
      const float* hp = hvp + tokc*128 + ks*32 + lgp*8;
      float4 lo = *(const float4*)hp;
      float4 hi = *(const float4*)(hp + 4);
      short8v ha;
      ha[0]=(short)f2bf(lo.x); ha[1]=(short)f2bf(lo.y);
      ha[2]=(short)f2bf(lo.z); ha[3]=(short)f2bf(lo.w);
      ha[4]=(short)f2bf(hi.x); ha[5]=(short)f2bf(hi.y);
      ha[6]=(short)f2bf(hi.z); ha[7]=(short)f2bf(hi.w);
      qacc = __builtin_amdgcn_mfma_f32_16x16x32_bf16(wq, ha, qacc, 0, 0, 0);
    }
    if (lm < 4) *(f32x4*)&qvp[lm*128 + wave*16 + lgp*4] = qacc;
  }

  __syncthreads();   // barrier 2: all Ab reads done -> safe to overlay KVs

  // ---- C writeout (verified swapped-operand mapping) ----
  #pragma unroll
  for (int m = 0; m < 4; ++m) {
    int row = mh*64 + m*16 + lm;
    #pragma unroll
    for (int n = 0; n < 4; ++n) {
      int col = nq*64 + n*16 + lgp*4;
      short4v p;
      p[0]=(short)f2bf(acc[m][n][0]); p[1]=(short)f2bf(acc[m][n][1]);
      p[2]=(short)f2bf(acc[m][n][2]); p[3]=(short)f2bf(acc[m][n][3]);
      *(short4v*)&KVs[row*ROWP + col] = p;
    }
  }
  __syncthreads();   // barrier 3: KVs + qvp visible

  // ---- logits + masked softmax (verbatim R11) ----
  {
    int tok = tid >> 7, h = (tid >> 5) & 3, k = tid & 31;
    int gtok = bn0 + tok;
    float s = 0.f;
    float ma = 0.f;
    if (k < TK) {
      const float* qp = &qvp[tok*128 + h*32];
      const unsigned short* kp = &KVs[(tok*TK + k)*ROWP + h*32];
      #pragma unroll
      for (int j = 0; j < 4; ++j) {
        short8v kf = *(const short8v*)(kp + j*8);
        float4 qa = *(const float4*)(qp + j*8);
        float4 qb = *(const float4*)(qp + j*8 + 4);
        s += qa.x*bf2f((unsigned short)kf[0]) + qa.y*bf2f((unsigned short)kf[1])
           + qa.z*bf2f((unsigned short)kf[2]) + qa.w*bf2f((unsigned short)kf[3])
           + qb.x*bf2f((unsigned short)kf[4]) + qb.y*bf2f((unsigned short)kf[5])
           + qb.z*bf2f((unsigned short)kf[6]) + qb.w*bf2f((unsigned short)kf[7]);
      }
      ma = mask_attend[(size_t)gtok*TK + k];
    }
    bool ok = (k < TK) && (ma > 0.f);
    float val = ok ? s * INV_SQRT_D : NEG_INF;
    float mm = val;
    #pragma unroll
    for (int d = 16; d >= 1; d >>= 1) mm = fmaxf(mm, __shfl_xor(mm, d, 32));
    float e = ok ? expf(val - mm) : 0.f;
    float ss = e;
    #pragma unroll
    for (int d = 16; d >= 1; d >>= 1) ss += __shfl_xor(ss, d, 32);
    att[(tok*4 + h)*32 + k] = e / ss;
  }
  __syncthreads();

  // ---- PV (verbatim R11) ----
  {
    int tok = tid >> 7, c = tid & 127;
    int gtok = bn0 + tok;
    const float* ar = &att[(tok*4 + (c >> 5))*32];
    const unsigned short* vb = &KVs[tok*TK*ROWP + TH + c];
    float u = 0.f;
    #pragma unroll
    for (int k = 0; k < TK; ++k)
      u += ar[k] * bf2f(vb[k*ROWP]);
    ul[(size_t)gtok*TH + c] = u;
  }
}

// ---------------------------------------------------------------------------
// K2: ffn_all (verbatim R11, verified).
// ---------------------------------------------------------------------------
__global__ __launch_bounds__(256) void ffn_all_kernel(
    const float* __restrict__ ul, const unsigned short* __restrict__ Wp2,
    const float* __restrict__ h_v,
    const float* __restrict__ gain0, const float* __restrict__ bias0,
    const unsigned short* __restrict__ Wi2, const unsigned short* __restrict__ Wo2,
    const float* __restrict__ b_in, const float* __restrict__ b_out,
    const float* __restrict__ gain1, const float* __restrict__ bias1,
    const float* __restrict__ mask_v, float* __restrict__ out)
{
  const int tid  = threadIdx.x;
  const int tok0 = blockIdx.x * 32;
  const int wave = tid >> 6;
  const int lane = tid & 63;
  const int lm   = lane & 15;
  const int lgp  = lane >> 4;

  __shared__ __align__(16) char smem[143616];
  unsigned short* Wp  = (unsigned short*)smem;            // 32 KB
  unsigned short* Wst = (unsigned short*)(smem + 32768);  // 64 KB dbuf
  unsigned short* At  = (unsigned short*)(smem + 98304);  // [32][136]
  unsigned short* Zs  = (unsigned short*)(smem + 107008); // [32][520]
  float* bin  = (float*)(smem + 140288);
  float* part = (float*)(smem + 142336);
  float* red  = (float*)(smem + 143360);

  for (int t = tid; t < 1024; t += 256) {
    int row = t >> 5, q = t & 31;
    float4 v = *(const float4*)&ul[(size_t)(tok0+row)*TH + q*4];
    short4v w;
    w[0]=(short)f2bf(v.x); w[1]=(short)f2bf(v.y);
    w[2]=(short)f2bf(v.z); w[3]=(short)f2bf(v.w);
    *(short4v*)&At[row*136 + q*4] = w;
  }
  if (tid < 128) *(float4*)&bin[tid*4] = *(const float4*)&b_in[tid*4];
  #pragma unroll
  for (int p = 0; p < 8; ++p)
    gload16(Wp2 + (size_t)(tid + p*256)*8, &Wp[(tid + p*256)*8]);
  #pragma unroll
  for (int p = 0; p < 8; ++p)
    gload16(Wi2 + (size_t)(tid + p*256)*8, &Wst[(tid + p*256)*8]);

  asm volatile("s_waitcnt vmcnt(8)" ::: "memory");
  __syncthreads();

  f32x4 acco[2][2] = {};
  #pragma unroll
  for (int ks = 0; ks < 4; ++ks) {
    short8v a0 = *(const short8v*)&At[lm*136      + ks*32 + lgp*8];
    short8v a1 = *(const short8v*)&At[(16+lm)*136 + ks*32 + lgp*8];
    #pragma unroll
    for (int n = 0; n < 2; ++n) {
      short8v b = *(const short8v*)&Wp[((size_t)(ks*8 + wave*2 + n)*64 + lane)*8];
      acco[0][n] = __builtin_amdgcn_mfma_f32_16x16x32_bf16(b, a0, acco[0][n], 0, 0, 0);
      acco[1][n] = __builtin_amdgcn_mfma_f32_16x16x32_bf16(b, a1, acco[1][n], 0, 0, 0);
    }
  }

  f32x4 hn[2][2];
  {
    f32x4 x[2][2];
    float s1r[2] = {0.f, 0.f}, s2r[2] = {0.f, 0.f};
    #pragma unroll
    for (int m = 0; m < 2; ++m) {
      int row = m*16 + lm;
      #pragma unroll
      for (int n = 0; n < 2; ++n) {
        int col = (wave*2 + n)*16 + lgp*4;
        float4 hv = *(const float4*)&h_v[(size_t)(tok0+row)*TH + col];
        x[m][n][0] = acco[m][n][0] + hv.x;
        x[m][n][1] = acco[m][n][1] + hv.y;
        x[m][n][2] = acco[m][n][2] + hv.z;
        x[m][n][3] = acco[m][n][3] + hv.w;
        #pragma unroll
        for (int r = 0; r < 4; ++r) {
          s1r[m] += x[m][n][r];
          s2r[m] += x[m][n][r]*x[m][n][r];
        }
      }
    }
    #pragma unroll
    for (int m = 0; m < 2; ++m) {
      s1r[m] += __shfl_xor(s1r[m], 16); s2r[m] += __shfl_xor(s2r[m], 16);
      s1r[m] += __shfl_xor(s1r[m], 32); s2r[m] += __shfl_xor(s2r[m], 32);
    }
    if (lgp == 0) {
      part[(lm*4      + wave)*2 + 0] = s1r[0];
      part[(lm*4      + wave)*2 + 1] = s2r[0];
      part[((16+lm)*4 + wave)*2 + 0] = s1r[1];
      part[((16+lm)*4 + wave)*2 + 1] = s2r[1];
    }
    __syncthreads();
    if (tid < 32) {
      float s1 = 0.f, s2 = 0.f;
      #pragma unroll
      for (int w = 0; w < 4; ++w) { s1 += part[(tid*4+w)*2]; s2 += part[(tid*4+w)*2+1]; }
      float mu  = s1*(1.f/128.f);
      float var = (s2 - 128.f*mu*mu)*(1.f/127.f);
      red[tid*2]   = mu;
      red[tid*2+1] = 1.f/(sqrtf(var+LN_EPS)+LN_EPS);
    }
    __syncthreads();
    #pragma unroll
    for (int m = 0; m < 2; ++m) {
      int row = m*16 + lm;
      float mu = red[row*2], inv = red[row*2+1];
      #pragma unroll
      for (int n = 0; n < 2; ++n) {
        int col = (wave*2 + n)*16 + lgp*4;
        float4 g = *(const float4*)&gain0[col];
        float4 b = *(const float4*)&bias0[col];
        hn[m][n][0] = g.x*(x[m][n][0]-mu)*inv + b.x;
        hn[m][n][1] = g.y*(x[m][n][1]-mu)*inv + b.y;
        hn[m][n][2] = g.z*(x[m][n][2]-mu)*inv + b.z;
        hn[m][n][3] = g.w*(x[m][n][3]-mu)*inv + b.w;
        short4v p;
        p[0]=(short)f2bf(hn[m][n][0]); p[1]=(short)f2bf(hn[m][n][1]);
        p[2]=(short)f2bf(hn[m][n][2]); p[3]=(short)f2bf(hn[m][n][3]);
        *(short4v*)&At[row*136 + col] = p;
      }
    }
  }

  f32x4 acc1[2][8] = {};
  #pragma unroll
  for (int ks = 0; ks < 4; ++ks) {
    asm volatile("s_waitcnt vmcnt(0)" ::: "memory");
    __builtin_amdgcn_s_barrier();
    if (ks < 3) {
      #pragma unroll
      for (int p = 0; p < 8; ++p)
        gload16(Wi2 + (size_t)(ks+1)*16384 + (tid + p*256)*8,
                &Wst[((ks+1)&1)*16384 + (tid + p*256)*8]);
    } else {
      #pragma unroll
      for (int p = 0; p < 4; ++p)
        gload16(Wo2 + (size_t)(tid + p*256)*8, &Wst[(tid + p*256)*8]);
    }

    short8v a0 = *(const short8v*)&At[lm*136      + ks*32 + lgp*8];
    short8v a1 = *(const short8v*)&At[(16+lm)*136 + ks*32 + lgp*8];
    #pragma unroll
    for (int n = 0; n < 8; ++n) {
      short8v b = *(const short8v*)&Wst[(ks&1)*16384 + ((wave*8 + n)*64 + lane)*8];
      acc1[0][n] = __builtin_amdgcn_mfma_f32_16x16x32_bf16(b, a0, acc1[0][n], 0, 0, 0);
      acc1[1][n] = __builtin_amdgcn_mfma_f32_16x16x32_bf16(b, a1, acc1[1][n], 0, 0, 0);
    }
  }

  #pragma unroll
  for (int m = 0; m < 2; ++m) {
    int row = m*16 + lm;
    #pragma unroll
    for (int n = 0; n < 8; ++n) {
      int col = (wave*8 + n)*16 + lgp*4;
      float4 bv = *(const float4*)&bin[col];
      short4v p;
      p[0]=(short)f2bf(fmaxf(acc1[m][n][0] + bv.x, 0.f));
      p[1]=(short)f2bf(fmaxf(acc1[m][n][1] + bv.y, 0.f));
      p[2]=(short)f2bf(fmaxf(acc1[m][n][2] + bv.z, 0.f));
      p[3]=(short)f2bf(fmaxf(acc1[m][n][3] + bv.w, 0.f));
      *(short4v*)&Zs[row*520 + col] = p;
    }
  }

  f32x4 acc2[2][2] = {};
  #pragma unroll
  for (int ks2 = 0; ks2 < 8; ++ks2) {
    asm volatile("s_waitcnt vmcnt(0)" ::: "memory");
    __builtin_amdgcn_s_barrier();
    if (ks2 < 7) {
      #pragma unroll
      for (int p = 0; p < 4; ++p)
        gload16(Wo2 + (size_t)(ks2+1)*8192 + (tid + p*256)*8,
                &Wst[((ks2+1)&1)*8192 + (tid + p*256)*8]);
    }

    #pragma unroll
    for (int s = 0; s < 2; ++s) {
      int ks = ks2*2 + s;
      short8v a0 = *(const short8v*)&Zs[lm*520      + ks*32 + lgp*8];
      short8v a1 = *(const short8v*)&Zs[(16+lm)*520 + ks*32 + lgp*8];
      #pragma unroll
      for (int n = 0; n < 2; ++n) {
        short8v b = *(const short8v*)&Wst[(ks2&1)*8192 + s*4096 + ((wave*2 + n)*64 + lane)*8];
        acc2[0][n] = __builtin_amdgcn_mfma_f32_16x16x32_bf16(b, a0, acc2[0][n], 0, 0, 0);
        acc2[1][n] = __builtin_amdgcn_mfma_f32_16x16x32_bf16(b, a1, acc2[1][n], 0, 0, 0);
      }
    }
  }

  {
    f32x4 x[2][2];
    float s1r[2] = {0.f, 0.f}, s2r[2] = {0.f, 0.f};
    #pragma unroll
    for (int m = 0; m < 2; ++m) {
      #pragma unroll
      for (int n = 0; n < 2; ++n) {
        int col = (wave*2 + n)*16 + lgp*4;
        float4 bo = *(const float4*)&b_out[col];
        x[m][n][0] = acc2[m][n][0] + bo.x + hn[m][n][0];
        x[m][n][1] = acc2[m][n][1] + bo.y + hn[m][n][1];
        x[m][n][2] = acc2[m][n][2] + bo.z + hn[m][n][2];
        x[m][n][3] = acc2[m][n][3] + bo.w + hn[m][n][3];
        #pragma unroll
        for (int r = 0; r < 4; ++r) {
          s1r[m] += x[m][n][r];
          s2r[m] += x[m][n][r]*x[m][n][r];
        }
      }
    }
    #pragma unroll
    for (int m = 0; m < 2; ++m) {
      s1r[m] += __shfl_xor(s1r[m], 16); s2r[m] += __shfl_xor(s2r[m], 16);
      s1r[m] += __shfl_xor(s1r[m], 32); s2r[m] += __shfl_xor(s2r[m], 32);
    }
    if (lgp == 0) {
      part[(lm*4      + wave)*2 + 0] = s1r[0];
      part[(lm*4      + wave)*2 + 1] = s2r[0];
      part[((16+lm)*4 + wave)*2 + 0] = s1r[1];
      part[((16+lm)*4 + wave)*2 + 1] = s2r[1];
    }
    __syncthreads();
    if (tid < 32) {
      float s1 = 0.f, s2 = 0.f;
      #pragma unroll
      for (int w = 0; w < 4; ++w) { s1 += part[(tid*4+w)*2]; s2 += part[(tid*4+w)*2+1]; }
      float mu  = s1*(1.f/128.f);
      float var = (s2 - 128.f*mu*mu)*(1.f/127.f);
      red[tid*2]   = mu;
      red[tid*2+1] = 1.f/(sqrtf(var+LN_EPS)+LN_EPS);
    }
    __syncthreads();
    #pragma unroll
    for (int m = 0; m < 2; ++m) {
      int row = m*16 + lm;
      float mu = red[row*2], inv = red[row*2+1];
      float mv = mask_v[tok0 + row];
      #pragma unroll
      for (int n = 0; n < 2; ++n) {
        int col = (wave*2 + n)*16 + lgp*4;
        float4 g = *(const float4*)&gain1[col];
        float4 b = *(const float4*)&bias1[col];
        float4 y;
        y.x = mv*(g.x*(x[m][n][0]-mu)*inv + b.x);
        y.y = mv*(g.y*(x[m][n][1]-mu)*inv + b.y);
        y.z = mv*(g.z*(x[m][n][2]-mu)*inv + b.z);
        y.w = mv*(g.w*(x[m][n][3]-mu)*inv + b.w);
        *(float4*)&out[(size_t)(tok0+row)*TH + col] = y;
      }
    }
  }
}

// ---------------------------------------------------------------------------
extern "C" void kernel_launch(void* const* d_in, const int* in_sizes, int n_in,
                              void* d_out, int out_size, void* d_ws, size_t ws_size,
                              hipStream_t stream)
{
  const float* h_v         = (const float*)d_in[0];
  const float* h_e         = (const float*)d_in[1];
  const float* mask_v      = (const float*)d_in[2];
  const float* mask_attend = (const float*)d_in[3];
  const float* W_Q   = (const float*)d_in[4];
  const float* W_K   = (const float*)d_in[5];
  const float* W_V   = (const float*)d_in[6];
  const float* W_O   = (const float*)d_in[7];
  const float* gain0 = (const float*)d_in[8];
  const float* bias0 = (const float*)d_in[9];
  const float* gain1 = (const float*)d_in[10];
  const float* bias1 = (const float*)d_in[11];
  const float* W_in  = (const float*)d_in[12];
  const float* b_in  = (const float*)d_in[13];
  const float* W_out = (const float*)d_in[14];
  const float* b_out = (const float*)d_in[15];

  float* out = (float*)d_out;
  char* ws = (char*)d_ws;
  unsigned short* Wc2 = (unsigned short*)ws;               //  131,072 B
  unsigned short* Wq2 = (unsigned short*)(ws + 131072);    //   32,768 B
  unsigned short* Wp2 = (unsigned short*)(ws + 163840);    //   32,768 B
  unsigned short* Wi2 = (unsigned short*)(ws + 196608);    //  131,072 B
  unsigned short* Wo2 = (unsigned short*)(ws + 327680);    //  131,072 B
  float* ul = (float*)(ws + 458752);                       // 4,096,000 B

  conv_weights_kernel<<<896, 256, 0, stream>>>(W_K, W_V, W_Q, W_O, W_in, W_out,
                                               Wc2, Wq2, Wp2, Wi2, Wo2);
  kvattn_kernel<<<NTOK/4, 512, 0, stream>>>(h_e, Wc2, Wq2, h_v, mask_attend, ul);
  ffn_all_kernel<<<NTOK/32, 256, 0, stream>>>(ul, Wp2, h_v, gain0, bias0,
                                              Wi2, Wo2, b_in, b_out,
                                              gain1, bias1, mask_v, out);
}

// Round 16
// 80.612 us; speedup vs baseline: 1.1532x; 1.0648x over previous
//
#include <hip/hip_runtime.h>
#include <math.h>

#define TK 30
#define TH 128
#define TNIN 256
#define TDFF 512
#define NTOK 8000
#define ROWP 264   // KVs row stride in u16

typedef __attribute__((ext_vector_type(8))) short short8v;
typedef __attribute__((ext_vector_type(4))) short short4v;
typedef __attribute__((ext_vector_type(4))) float f32x4;

constexpr float LN_EPS = 1e-6f;
constexpr float NEG_INF = -3.402823466e38f;
constexpr float INV_SQRT_D = 0.17677669529663687f;  // 1/sqrt(32)

static __device__ __forceinline__ unsigned short f2bf(float f) {
  unsigned u = __float_as_uint(f);
  u = u + 0x7fffu + ((u >> 16) & 1u);
  return (unsigned short)(u >> 16);
}
static __device__ __forceinline__ float bf2f(unsigned short s) {
  return __uint_as_float(((unsigned)s) << 16);
}
static __device__ __forceinline__ void gload16(const void* gsrc, void* ldst) {
  __builtin_amdgcn_global_load_lds(
      (const __attribute__((address_space(1))) unsigned int*)gsrc,
      (__attribute__((address_space(3))) unsigned int*)ldst, 16, 0, 0);
}

// ---------------------------------------------------------------------------
// K0: weight prep (verified). Frag-linear bf16:
//   elem ((ks*NF + n)*64 + lane)*8 + j = W[n*16+(lane&15)][ks*32+(lane>>4)*8+j]
// ---------------------------------------------------------------------------
__global__ void conv_weights_kernel(const float* __restrict__ W_K,
                                    const float* __restrict__ W_V,
                                    const float* __restrict__ W_Q,
                                    const float* __restrict__ W_O,
                                    const float* __restrict__ W_in,
                                    const float* __restrict__ W_out,
                                    unsigned short* __restrict__ Wc2,
                                    unsigned short* __restrict__ Wq2,
                                    unsigned short* __restrict__ Wp2,
                                    unsigned short* __restrict__ Wi2,
                                    unsigned short* __restrict__ Wo2)
{
  int idx = blockIdx.x * 256 + threadIdx.x;   // 0..229375
  if (idx < 65536) {
    int e = idx >> 3, j = idx & 7;
    int kk = e >> 10, n = (e >> 6) & 15, lane = e & 63;
    int r = n*16 + (lane & 15);
    int c = kk*32 + (lane >> 4)*8 + j;
    float v = (r < TH) ? W_K[(size_t)r*TNIN + c] : W_V[(size_t)(r-TH)*TNIN + c];
    Wc2[idx] = f2bf(v);
  } else if (idx < 81920) {
    int i2 = idx - 65536;
    int e = i2 >> 3, j = i2 & 7;
    int kk = e >> 9, n = (e >> 6) & 7, lane = e & 63;
    int r = n*16 + (lane & 15);
    int c = kk*32 + (lane >> 4)*8 + j;
    Wq2[i2] = f2bf(W_Q[(size_t)r*TH + c]);
  } else if (idx < 98304) {
    int ip = idx - 81920;
    int e = ip >> 3, j = ip & 7;
    int kk = e >> 9, n = (e >> 6) & 7, lane = e & 63;
    int r = n*16 + (lane & 15);
    int c = kk*32 + (lane >> 4)*8 + j;
    Wp2[ip] = f2bf(W_O[(size_t)r*TH + c]);
  } else if (idx < 163840) {
    int i3 = idx - 98304;
    int e = i3 >> 3, j = i3 & 7;
    int ks = e >> 11, n = (e >> 6) & 31, lane = e & 63;
    int r = n*16 + (lane & 15);
    int c = ks*32 + (lane >> 4)*8 + j;
    Wi2[i3] = f2bf(W_in[(size_t)r*TH + c]);
  } else {
    int i4 = idx - 163840;
    int e = i4 >> 3, j = i4 & 7;
    int ks = e >> 9, n = (e >> 6) & 7, lane = e & 63;
    int r = n*16 + (lane & 15);
    int c = ks*32 + (lane >> 4)*8 + j;
    Wo2[i4] = f2bf(W_out[(size_t)r*TDFF + c]);
  }
}

// ---------------------------------------------------------------------------
// K1: fused Q-proj + KV-GEMM + attention core (R11 structure, best measured).
// ---------------------------------------------------------------------------
__global__ __launch_bounds__(512, 4) void kvattn_kernel(
    const float* __restrict__ A, const unsigned short* __restrict__ Wc2,
    const unsigned short* __restrict__ Wq2, const float* __restrict__ h_v,
    const float* __restrict__ mask_attend, float* __restrict__ ul)
{
  const int tid  = threadIdx.x;
  const int wave = tid >> 6;
  const int lane = tid & 63;
  const int lm   = lane & 15;
  const int lgp  = lane >> 4;
  const int mh   = wave >> 2;   // 0..1
  const int nq   = wave & 3;    // 0..3
  const int bn0  = blockIdx.x * 4;

  __shared__ __align__(16) char smem[73728];
  unsigned short* Bl  = (unsigned short*)smem;          // [3][8192]   0..49152
  unsigned short* Al  = (unsigned short*)(smem + 49152);// [2][128][40] ..69632
  unsigned short* KVs = (unsigned short*)smem;          // [128][264] overlay 0..67584
  float* att = (float*)(smem + 67584);                  // [4][4][32] (Al tail, dead)
  float* hvp = (float*)(smem + 69632);                  // [4][128] f32
  float* qvp = (float*)(smem + 71680);                  // [4][128] f32

  // ---- prologue extras: h_v to LDS (visible after first loop barrier) ----
  if (tid < 128) {
    int tok = tid >> 5, q = tid & 31;
    *(float4*)&hvp[tok*128 + q*4] = *(const float4*)&h_v[(size_t)(bn0 + tok)*TH + q*4];
  }

  const int rowa = tid >> 2, cga = tid & 3;
  const int rowc = (rowa > 119) ? 119 : rowa;
  const float* aptr = A + ((size_t)blockIdx.x*120 + rowc)*TNIN + cga*8;

  #define ISSUE_B(K)                                                             \
    { gload16(Wc2 + (size_t)(K)*8192 + tid*8,       &Bl[((K)%3)*8192 + tid*8]);  \
      gload16(Wc2 + (size_t)(K)*8192 + (tid+512)*8, &Bl[((K)%3)*8192 + (tid+512)*8]); }

  #define WRITE_A(K, S)                                                     \
    { short8v w;                                                            \
      w[0]=(short)f2bf(ra[S][0].x); w[1]=(short)f2bf(ra[S][0].y);           \
      w[2]=(short)f2bf(ra[S][0].z); w[3]=(short)f2bf(ra[S][0].w);           \
      w[4]=(short)f2bf(ra[S][1].x); w[5]=(short)f2bf(ra[S][1].y);           \
      w[6]=(short)f2bf(ra[S][1].z); w[7]=(short)f2bf(ra[S][1].w);           \
      *(short8v*)&Al[(((K)&1)*128 + rowa)*40 + cga*8] = w; }

  float4 ra[3][2];
  f32x4 acc[4][4] = {};

  // prologue: rA(0); B(0); B(1); rA(1); rA(2); write A(0)
  ra[0][0] = *(const float4*)(aptr + 0);
  ra[0][1] = *(const float4*)(aptr + 4);
  ISSUE_B(0);
  ISSUE_B(1);
  ra[1][0] = *(const float4*)(aptr + 32);
  ra[1][1] = *(const float4*)(aptr + 36);
  ra[2][0] = *(const float4*)(aptr + 64);
  ra[2][1] = *(const float4*)(aptr + 68);
  WRITE_A(0, 0);

  #pragma unroll
  for (int k = 0; k < 8; ++k) {
    if (k == 7)      asm volatile("s_waitcnt vmcnt(0)" ::: "memory");
    else if (k == 6) asm volatile("s_waitcnt vmcnt(4)" ::: "memory");
    else             asm volatile("s_waitcnt vmcnt(6)" ::: "memory");
    __builtin_amdgcn_s_barrier();

    if (k < 6) ISSUE_B(k+2);
    if (k < 5) {
      ra[k%3][0] = *(const float4*)(aptr + (k+3)*32);
      ra[k%3][1] = *(const float4*)(aptr + (k+3)*32 + 4);
    }

    short8v af[4];
    #pragma unroll
    for (int m = 0; m < 4; ++m)
      af[m] = *(const short8v*)&Al[((k&1)*128 + mh*64 + m*16 + lm)*40 + lgp*8];

    __builtin_amdgcn_s_setprio(1);
    #pragma unroll
    for (int n = 0; n < 4; ++n) {
      short8v b = *(const short8v*)&Bl[(k%3)*8192 + ((nq*4 + n)*64 + lane)*8];
      #pragma unroll
      for (int m = 0; m < 4; ++m)
        acc[m][n] = __builtin_amdgcn_mfma_f32_16x16x32_bf16(b, af[m], acc[m][n], 0, 0, 0);
    }
    __builtin_amdgcn_s_setprio(0);

    if (k < 7) WRITE_A(k+1, (k+1)%3);
  }
  #undef ISSUE_B
  #undef WRITE_A

  __syncthreads();   // all Bl/Al reads done before KVs overlay

  // ---- C writeout (verified swapped-operand mapping) ----
  #pragma unroll
  for (int m = 0; m < 4; ++m) {
    int row = mh*64 + m*16 + lm;
    #pragma unroll
    for (int n = 0; n < 4; ++n) {
      int col = nq*64 + n*16 + lgp*4;
      short4v p;
      p[0]=(short)f2bf(acc[m][n][0]); p[1]=(short)f2bf(acc[m][n][1]);
      p[2]=(short)f2bf(acc[m][n][2]); p[3]=(short)f2bf(acc[m][n][3]);
      *(short4v*)&KVs[row*ROWP + col] = p;
    }
  }

  // ---- Q = h_v @ W_Q^T (acc dead; wq loaded here from L2) ----
  {
    f32x4 qacc = {};
    const int tokc = (lm < 4) ? lm : 3;
    #pragma unroll
    for (int ks = 0; ks < 4; ++ks) {
      short8v wq = *(const short8v*)(Wq2 + ((size_t)(ks*8 + wave)*64 + lane)*8);
      const float* hp = hvp + tokc*128 + ks*32 + lgp*8;
      float4 lo = *(const float4*)hp;
      float4 hi = *(const float4*)(hp + 4);
      short8v ha;
      ha[0]=(short)f2bf(lo.x); ha[1]=(short)f2bf(lo.y);
      ha[2]=(short)f2bf(lo.z); ha[3]=(short)f2bf(lo.w);
      ha[4]=(short)f2bf(hi.x); ha[5]=(short)f2bf(hi.y);
      ha[6]=(short)f2bf(hi.z); ha[7]=(short)f2bf(hi.w);
      qacc = __builtin_amdgcn_mfma_f32_16x16x32_bf16(wq, ha, qacc, 0, 0, 0);
    }
    if (lm < 4) *(f32x4*)&qvp[lm*128 + wave*16 + lgp*4] = qacc;
  }
  __syncthreads();   // KVs + qvp visible

  // ---- logits + masked softmax ----
  {
    int tok = tid >> 7, h = (tid >> 5) & 3, k = tid & 31;
    int gtok = bn0 + tok;
    float s = 0.f;
    float ma = 0.f;
    if (k < TK) {
      const float* qp = &qvp[tok*128 + h*32];
      const unsigned short* kp = &KVs[(tok*TK + k)*ROWP + h*32];
      #pragma unroll
      for (int j = 0; j < 4; ++j) {
        short8v kf = *(const short8v*)(kp + j*8);
        float4 qa = *(const float4*)(qp + j*8);
        float4 qb = *(const float4*)(qp + j*8 + 4);
        s += qa.x*bf2f((unsigned short)kf[0]) + qa.y*bf2f((unsigned short)kf[1])
           + qa.z*bf2f((unsigned short)kf[2]) + qa.w*bf2f((unsigned short)kf[3])
           + qb.x*bf2f((unsigned short)kf[4]) + qb.y*bf2f((unsigned short)kf[5])
           + qb.z*bf2f((unsigned short)kf[6]) + qb.w*bf2f((unsigned short)kf[7]);
      }
      ma = mask_attend[(size_t)gtok*TK + k];
    }
    bool ok = (k < TK) && (ma > 0.f);
    float val = ok ? s * INV_SQRT_D : NEG_INF;
    float mm = val;
    #pragma unroll
    for (int d = 16; d >= 1; d >>= 1) mm = fmaxf(mm, __shfl_xor(mm, d, 32));
    float e = ok ? expf(val - mm) : 0.f;
    float ss = e;
    #pragma unroll
    for (int d = 16; d >= 1; d >>= 1) ss += __shfl_xor(ss, d, 32);
    att[(tok*4 + h)*32 + k] = e / ss;
  }
  __syncthreads();

  // ---- PV ----
  {
    int tok = tid >> 7, c = tid & 127;
    int gtok = bn0 + tok;
    const float* ar = &att[(tok*4 + (c >> 5))*32];
    const unsigned short* vb = &KVs[tok*TK*ROWP + TH + c];
    float u = 0.f;
    #pragma unroll
    for (int k = 0; k < TK; ++k)
      u += ar[k] * bf2f(vb[k*ROWP]);
    ul[(size_t)gtok*TH + c] = u;
  }
}

// ---------------------------------------------------------------------------
// K2: ffn_all (R11, verified: pipelined weight staging, 1 block/CU).
// ---------------------------------------------------------------------------
__global__ __launch_bounds__(256) void ffn_all_kernel(
    const float* __restrict__ ul, const unsigned short* __restrict__ Wp2,
    const float* __restrict__ h_v,
    const float* __restrict__ gain0, const float* __restrict__ bias0,
    const unsigned short* __restrict__ Wi2, const unsigned short* __restrict__ Wo2,
    const float* __restrict__ b_in, const float* __restrict__ b_out,
    const float* __restrict__ gain1, const float* __restrict__ bias1,
    const float* __restrict__ mask_v, float* __restrict__ out)
{
  const int tid  = threadIdx.x;
  const int tok0 = blockIdx.x * 32;
  const int wave = tid >> 6;
  const int lane = tid & 63;
  const int lm   = lane & 15;
  const int lgp  = lane >> 4;

  __shared__ __align__(16) char smem[143616];
  unsigned short* Wp  = (unsigned short*)smem;            // 32 KB
  unsigned short* Wst = (unsigned short*)(smem + 32768);  // 64 KB dbuf
  unsigned short* At  = (unsigned short*)(smem + 98304);  // [32][136]
  unsigned short* Zs  = (unsigned short*)(smem + 107008); // [32][520]
  float* bin  = (float*)(smem + 140288);
  float* part = (float*)(smem + 142336);
  float* red  = (float*)(smem + 143360);

  for (int t = tid; t < 1024; t += 256) {
    int row = t >> 5, q = t & 31;
    float4 v = *(const float4*)&ul[(size_t)(tok0+row)*TH + q*4];
    short4v w;
    w[0]=(short)f2bf(v.x); w[1]=(short)f2bf(v.y);
    w[2]=(short)f2bf(v.z); w[3]=(short)f2bf(v.w);
    *(short4v*)&At[row*136 + q*4] = w;
  }
  if (tid < 128) *(float4*)&bin[tid*4] = *(const float4*)&b_in[tid*4];
  #pragma unroll
  for (int p = 0; p < 8; ++p)
    gload16(Wp2 + (size_t)(tid + p*256)*8, &Wp[(tid + p*256)*8]);
  #pragma unroll
  for (int p = 0; p < 8; ++p)
    gload16(Wi2 + (size_t)(tid + p*256)*8, &Wst[(tid + p*256)*8]);

  asm volatile("s_waitcnt vmcnt(8)" ::: "memory");
  __syncthreads();

  f32x4 acco[2][2] = {};
  #pragma unroll
  for (int ks = 0; ks < 4; ++ks) {
    short8v a0 = *(const short8v*)&At[lm*136      + ks*32 + lgp*8];
    short8v a1 = *(const short8v*)&At[(16+lm)*136 + ks*32 + lgp*8];
    #pragma unroll
    for (int n = 0; n < 2; ++n) {
      short8v b = *(const short8v*)&Wp[((size_t)(ks*8 + wave*2 + n)*64 + lane)*8];
      acco[0][n] = __builtin_amdgcn_mfma_f32_16x16x32_bf16(b, a0, acco[0][n], 0, 0, 0);
      acco[1][n] = __builtin_amdgcn_mfma_f32_16x16x32_bf16(b, a1, acco[1][n], 0, 0, 0);
    }
  }

  f32x4 hn[2][2];
  {
    f32x4 x[2][2];
    float s1r[2] = {0.f, 0.f}, s2r[2] = {0.f, 0.f};
    #pragma unroll
    for (int m = 0; m < 2; ++m) {
      int row = m*16 + lm;
      #pragma unroll
      for (int n = 0; n < 2; ++n) {
        int col = (wave*2 + n)*16 + lgp*4;
        float4 hv = *(const float4*)&h_v[(size_t)(tok0+row)*TH + col];
        x[m][n][0] = acco[m][n][0] + hv.x;
        x[m][n][1] = acco[m][n][1] + hv.y;
        x[m][n][2] = acco[m][n][2] + hv.z;
        x[m][n][3] = acco[m][n][3] + hv.w;
        #pragma unroll
        for (int r = 0; r < 4; ++r) {
          s1r[m] += x[m][n][r];
          s2r[m] += x[m][n][r]*x[m][n][r];
        }
      }
    }
    #pragma unroll
    for (int m = 0; m < 2; ++m) {
      s1r[m] += __shfl_xor(s1r[m], 16); s2r[m] += __shfl_xor(s2r[m], 16);
      s1r[m] += __shfl_xor(s1r[m], 32); s2r[m] += __shfl_xor(s2r[m], 32);
    }
    if (lgp == 0) {
      part[(lm*4      + wave)*2 + 0] = s1r[0];
      part[(lm*4      + wave)*2 + 1] = s2r[0];
      part[((16+lm)*4 + wave)*2 + 0] = s1r[1];
      part[((16+lm)*4 + wave)*2 + 1] = s2r[1];
    }
    __syncthreads();
    if (tid < 32) {
      float s1 = 0.f, s2 = 0.f;
      #pragma unroll
      for (int w = 0; w < 4; ++w) { s1 += part[(tid*4+w)*2]; s2 += part[(tid*4+w)*2+1]; }
      float mu  = s1*(1.f/128.f);
      float var = (s2 - 128.f*mu*mu)*(1.f/127.f);
      red[tid*2]   = mu;
      red[tid*2+1] = 1.f/(sqrtf(var+LN_EPS)+LN_EPS);
    }
    __syncthreads();
    #pragma unroll
    for (int m = 0; m < 2; ++m) {
      int row = m*16 + lm;
      float mu = red[row*2], inv = red[row*2+1];
      #pragma unroll
      for (int n = 0; n < 2; ++n) {
        int col = (wave*2 + n)*16 + lgp*4;
        float4 g = *(const float4*)&gain0[col];
        float4 b = *(const float4*)&bias0[col];
        hn[m][n][0] = g.x*(x[m][n][0]-mu)*inv + b.x;
        hn[m][n][1] = g.y*(x[m][n][1]-mu)*inv + b.y;
        hn[m][n][2] = g.z*(x[m][n][2]-mu)*inv + b.z;
        hn[m][n][3] = g.w*(x[m][n][3]-mu)*inv + b.w;
        short4v p;
        p[0]=(short)f2bf(hn[m][n][0]); p[1]=(short)f2bf(hn[m][n][1]);
        p[2]=(short)f2bf(hn[m][n][2]); p[3]=(short)f2bf(hn[m][n][3]);
        *(short4v*)&At[row*136 + col] = p;
      }
    }
  }

  // ---- GEMM1: Z = relu(Hn @ W_in^T + b_in); pipelined stages ----
  f32x4 acc1[2][8] = {};
  #pragma unroll
  for (int ks = 0; ks < 4; ++ks) {
    asm volatile("s_waitcnt vmcnt(0)" ::: "memory");
    __builtin_amdgcn_s_barrier();
    if (ks < 3) {
      #pragma unroll
      for (int p = 0; p < 8; ++p)
        gload16(Wi2 + (size_t)(ks+1)*16384 + (tid + p*256)*8,
                &Wst[((ks+1)&1)*16384 + (tid + p*256)*8]);
    } else {
      #pragma unroll
      for (int p = 0; p < 4; ++p)
        gload16(Wo2 + (size_t)(tid + p*256)*8, &Wst[(tid + p*256)*8]);
    }

    short8v a0 = *(const short8v*)&At[lm*136      + ks*32 + lgp*8];
    short8v a1 = *(const short8v*)&At[(16+lm)*136 + ks*32 + lgp*8];
    #pragma unroll
    for (int n = 0; n < 8; ++n) {
      short8v b = *(const short8v*)&Wst[(ks&1)*16384 + ((wave*8 + n)*64 + lane)*8];
      acc1[0][n] = __builtin_amdgcn_mfma_f32_16x16x32_bf16(b, a0, acc1[0][n], 0, 0, 0);
      acc1[1][n] = __builtin_amdgcn_mfma_f32_16x16x32_bf16(b, a1, acc1[1][n], 0, 0, 0);
    }
  }

  #pragma unroll
  for (int m = 0; m < 2; ++m) {
    int row = m*16 + lm;
    #pragma unroll
    for (int n = 0; n < 8; ++n) {
      int col = (wave*8 + n)*16 + lgp*4;
      float4 bv = *(const float4*)&bin[col];
      short4v p;
      p[0]=(short)f2bf(fmaxf(acc1[m][n][0] + bv.x, 0.f));
      p[1]=(short)f2bf(fmaxf(acc1[m][n][1] + bv.y, 0.f));
      p[2]=(short)f2bf(fmaxf(acc1[m][n][2] + bv.z, 0.f));
      p[3]=(short)f2bf(fmaxf(acc1[m][n][3] + bv.w, 0.f));
      *(short4v*)&Zs[row*520 + col] = p;
    }
  }

  // ---- GEMM2: Y = Z @ W_out^T (8 stages x 2 sub-ks); pipelined ----
  f32x4 acc2[2][2] = {};
  #pragma unroll
  for (int ks2 = 0; ks2 < 8; ++ks2) {
    asm volatile("s_waitcnt vmcnt(0)" ::: "memory");
    __builtin_amdgcn_s_barrier();
    if (ks2 < 7) {
      #pragma unroll
      for (int p = 0; p < 4; ++p)
        gload16(Wo2 + (size_t)(ks2+1)*8192 + (tid + p*256)*8,
                &Wst[((ks2+1)&1)*8192 + (tid + p*256)*8]);
    }

    #pragma unroll
    for (int s = 0; s < 2; ++s) {
      int ks = ks2*2 + s;
      short8v a0 = *(const short8v*)&Zs[lm*520      + ks*32 + lgp*8];
      short8v a1 = *(const short8v*)&Zs[(16+lm)*520 + ks*32 + lgp*8];
      #pragma unroll
      for (int n = 0; n < 2; ++n) {
        short8v b = *(const short8v*)&Wst[(ks2&1)*8192 + s*4096 + ((wave*2 + n)*64 + lane)*8];
        acc2[0][n] = __builtin_amdgcn_mfma_f32_16x16x32_bf16(b, a0, acc2[0][n], 0, 0, 0);
        acc2[1][n] = __builtin_amdgcn_mfma_f32_16x16x32_bf16(b, a1, acc2[1][n], 0, 0, 0);
      }
    }
  }

  // ---- x2 = Y + b_out + Hn(regs); LN1; mask; store ----
  {
    f32x4 x[2][2];
    float s1r[2] = {0.f, 0.f}, s2r[2] = {0.f, 0.f};
    #pragma unroll
    for (int m = 0; m < 2; ++m) {
      #pragma unroll
      for (int n = 0; n < 2; ++n) {
        int col = (wave*2 + n)*16 + lgp*4;
        float4 bo = *(const float4*)&b_out[col];
        x[m][n][0] = acc2[m][n][0] + bo.x + hn[m][n][0];
        x[m][n][1] = acc2[m][n][1] + bo.y + hn[m][n][1];
        x[m][n][2] = acc2[m][n][2] + bo.z + hn[m][n][2];
        x[m][n][3] = acc2[m][n][3] + bo.w + hn[m][n][3];
        #pragma unroll
        for (int r = 0; r < 4; ++r) {
          s1r[m] += x[m][n][r];
          s2r[m] += x[m][n][r]*x[m][n][r];
        }
      }
    }
    #pragma unroll
    for (int m = 0; m < 2; ++m) {
      s1r[m] += __shfl_xor(s1r[m], 16); s2r[m] += __shfl_xor(s2r[m], 16);
      s1r[m] += __shfl_xor(s1r[m], 32); s2r[m] += __shfl_xor(s2r[m], 32);
    }
    if (lgp == 0) {
      part[(lm*4      + wave)*2 + 0] = s1r[0];
      part[(lm*4      + wave)*2 + 1] = s2r[0];
      part[((16+lm)*4 + wave)*2 + 0] = s1r[1];
      part[((16+lm)*4 + wave)*2 + 1] = s2r[1];
    }
    __syncthreads();
    if (tid < 32) {
      float s1 = 0.f, s2 = 0.f;
      #pragma unroll
      for (int w = 0; w < 4; ++w) { s1 += part[(tid*4+w)*2]; s2 += part[(tid*4+w)*2+1]; }
      float mu  = s1*(1.f/128.f);
      float var = (s2 - 128.f*mu*mu)*(1.f/127.f);
      red[tid*2]   = mu;
      red[tid*2+1] = 1.f/(sqrtf(var+LN_EPS)+LN_EPS);
    }
    __syncthreads();
    #pragma unroll
    for (int m = 0; m < 2; ++m) {
      int row = m*16 + lm;
      float mu = red[row*2], inv = red[row*2+1];
      float mv = mask_v[tok0 + row];
      #pragma unroll
      for (int n = 0; n < 2; ++n) {
        int col = (wave*2 + n)*16 + lgp*4;
        float4 g = *(const float4*)&gain1[col];
        float4 b = *(const float4*)&bias1[col];
        float4 y;
        y.x = mv*(g.x*(x[m][n][0]-mu)*inv + b.x);
        y.y = mv*(g.y*(x[m][n][1]-mu)*inv + b.y);
        y.z = mv*(g.z*(x[m][n][2]-mu)*inv + b.z);
        y.w = mv*(g.w*(x[m][n][3]-mu)*inv + b.w);
        *(float4*)&out[(size_t)(tok0+row)*TH + col] = y;
      }
    }
  }
}

// ---------------------------------------------------------------------------
extern "C" void kernel_launch(void* const* d_in, const int* in_sizes, int n_in,
                              void* d_out, int out_size, void* d_ws, size_t ws_size,
                              hipStream_t stream)
{
  const float* h_v         = (const float*)d_in[0];
  const float* h_e         = (const float*)d_in[1];
  const float* mask_v      = (const float*)d_in[2];
  const float* mask_attend = (const float*)d_in[3];
  const float* W_Q   = (const float*)d_in[4];
  const float* W_K   = (const float*)d_in[5];
  const float* W_V   = (const float*)d_in[6];
  const float* W_O   = (const float*)d_in[7];
  const float* gain0 = (const float*)d_in[8];
  const float* bias0 = (const float*)d_in[9];
  const float* gain1 = (const float*)d_in[10];
  const float* bias1 = (const float*)d_in[11];
  const float* W_in  = (const float*)d_in[12];
  const float* b_in  = (const float*)d_in[13];
  const float* W_out = (const float*)d_in[14];
  const float* b_out = (const float*)d_in[15];

  float* out = (float*)d_out;
  char* ws = (char*)d_ws;
  unsigned short* Wc2 = (unsigned short*)ws;               //  131,072 B
  unsigned short* Wq2 = (unsigned short*)(ws + 131072);    //   32,768 B
  unsigned short* Wp2 = (unsigned short*)(ws + 163840);    //   32,768 B
  unsigned short* Wi2 = (unsigned short*)(ws + 196608);    //  131,072 B
  unsigned short* Wo2 = (unsigned short*)(ws + 327680);    //  131,072 B
  float* ul = (float*)(ws + 458752);                       // 4,096,000 B

  conv_weights_kernel<<<896, 256, 0, stream>>>(W_K, W_V, W_Q, W_O, W_in, W_out,
                                               Wc2, Wq2, Wp2, Wi2, Wo2);
  kvattn_kernel<<<NTOK/4, 512, 0, stream>>>(h_e, Wc2, Wq2, h_v, mask_attend, ul);
  ffn_all_kernel<<<NTOK/32, 256, 0, stream>>>(ul, Wp2, h_v, gain0, bias0,
                                              Wi2, Wo2, b_in, b_out,
                                              gain1, bias1, mask_v, out);
}